// Round 1
// baseline (1294.604 us; speedup 1.0000x reference)
//
#include <hip/hip_runtime.h>

typedef __attribute__((ext_vector_type(8))) short short8;
typedef __attribute__((ext_vector_type(4))) float f32x4;
typedef __attribute__((ext_vector_type(4))) int int4v;

#define DIMD 512
#define EE 1024
#define SSS 128
#define LLL 4096
#define NROW 16384   // B*L
#define NUV 2176     // 2E+S

__device__ __forceinline__ short f2bf(float f) {
  union { float f; unsigned u; } un; un.f = f;
  unsigned r = un.u + 0x7FFFu + ((un.u >> 16) & 1u);
  return (short)(r >> 16);
}
__device__ __forceinline__ float bf2f(short s) {
  union { unsigned u; float f; } un;
  un.u = ((unsigned)(unsigned short)s) << 16;
  return un.f;
}
__device__ __forceinline__ float silu_f(float x) {
  return x / (1.0f + __expf(-x));
}

// ---------------- prep: transpose+cast weights to bf16 ----------------
__global__ void prep_kernel(const float* __restrict__ W_uv, const float* __restrict__ W_out,
                            short* __restrict__ W_uvT, short* __restrict__ W_outT) {
  int i = blockIdx.x * blockDim.x + threadIdx.x;
  if (i < NUV * DIMD) {            // W_uvT[c][d] = W_uv[d][c]
    int c = i >> 9, d = i & (DIMD - 1);
    W_uvT[i] = f2bf(W_uv[(size_t)d * NUV + c]);
  }
  if (i < DIMD * EE) {             // W_outT[d][e] = W_out[e][d]
    int d = i >> 10, e = i & (EE - 1);
    W_outT[i] = f2bf(W_out[(size_t)e * DIMD + d]);
  }
}

// ---------------- layernorm -> xn bf16 ----------------
__global__ __launch_bounds__(256) void ln_kernel(const float* __restrict__ x,
    const float* __restrict__ w, const float* __restrict__ bb, short* __restrict__ xn) {
  int row = blockIdx.x;
  int tid = threadIdx.x;
  const float2* xr = (const float2*)(x + (size_t)row * DIMD);
  float2 v = xr[tid];
  float s = v.x + v.y, ss = v.x * v.x + v.y * v.y;
  #pragma unroll
  for (int off = 32; off >= 1; off >>= 1) {
    s += __shfl_down(s, off);
    ss += __shfl_down(ss, off);
  }
  __shared__ float ps[8];
  if ((tid & 63) == 0) { ps[tid >> 6] = s; ps[4 + (tid >> 6)] = ss; }
  __syncthreads();
  s = ps[0] + ps[1] + ps[2] + ps[3];
  ss = ps[4] + ps[5] + ps[6] + ps[7];
  float mu = s * (1.0f / DIMD);
  float var = ss * (1.0f / DIMD) - mu * mu;
  float inv = rsqrtf(var + 1e-5f);
  float2 wv = ((const float2*)w)[tid];
  float2 bv = ((const float2*)bb)[tid];
  short2 o;
  o.x = f2bf((v.x - mu) * inv * wv.x + bv.x);
  o.y = f2bf((v.y - mu) * inv * wv.y + bv.y);
  *(short2*)&xn[(size_t)row * DIMD + tid * 2] = o;
}

// ---------------- GEMM1: xn[16384,512] x W_uvT[2176,512] + fused epilogue ----------------
__global__ __launch_bounds__(256) void gemm_uv_kernel(
    const short* __restrict__ A, const short* __restrict__ Bw,
    const float* __restrict__ b_uv, const float* __restrict__ gamma, const float* __restrict__ beta,
    short* __restrict__ u_out, short* __restrict__ vT_out,
    short* __restrict__ q_out, short* __restrict__ k_out)
{
  __shared__ __align__(16) short As[64][40];
  __shared__ __align__(16) short Bs[64][40];
  int m0 = blockIdx.x * 64, n0 = blockIdx.y * 64;
  int tid = threadIdx.x, wid = tid >> 6, lane = tid & 63;
  int wr = (wid >> 1) * 32, wc = (wid & 1) * 32;
  int srow = tid >> 2, scol = (tid & 3) * 8;
  int lr = lane & 15, lk = (lane >> 4) * 8;
  f32x4 acc[2][2];
  #pragma unroll
  for (int i = 0; i < 2; i++)
    #pragma unroll
    for (int j = 0; j < 2; j++) acc[i][j] = (f32x4){0.f, 0.f, 0.f, 0.f};
  for (int k0 = 0; k0 < DIMD; k0 += 32) {
    *(int4v*)&As[srow][scol] = *(const int4v*)&A[(size_t)(m0 + srow) * DIMD + k0 + scol];
    *(int4v*)&Bs[srow][scol] = *(const int4v*)&Bw[(size_t)(n0 + srow) * DIMD + k0 + scol];
    __syncthreads();
    short8 a0 = *(short8*)&As[wr + lr][lk];
    short8 a1 = *(short8*)&As[wr + 16 + lr][lk];
    short8 b0 = *(short8*)&Bs[wc + lr][lk];
    short8 b1 = *(short8*)&Bs[wc + 16 + lr][lk];
    acc[0][0] = __builtin_amdgcn_mfma_f32_16x16x32_bf16(a0, b0, acc[0][0], 0, 0, 0);
    acc[0][1] = __builtin_amdgcn_mfma_f32_16x16x32_bf16(a0, b1, acc[0][1], 0, 0, 0);
    acc[1][0] = __builtin_amdgcn_mfma_f32_16x16x32_bf16(a1, b0, acc[1][0], 0, 0, 0);
    acc[1][1] = __builtin_amdgcn_mfma_f32_16x16x32_bf16(a1, b1, acc[1][1], 0, 0, 0);
    __syncthreads();
  }
  #pragma unroll
  for (int i = 0; i < 2; i++) {
    #pragma unroll
    for (int j = 0; j < 2; j++) {
      int col = n0 + wc + j * 16 + lr;
      float bias = b_uv[col];
      #pragma unroll
      for (int r = 0; r < 4; r++) {
        int row = m0 + wr + i * 16 + (lane >> 4) * 4 + r;
        float val = acc[i][j][r] + bias;
        if (col < EE) {
          u_out[(size_t)row * EE + col] = f2bf(silu_f(val));
        } else if (col < 2 * EE) {
          int e = col - EE, bb = row >> 12, lb = row & (LLL - 1);
          vT_out[((size_t)bb * EE + e) * LLL + lb] = f2bf(silu_f(val));
        } else {
          int s = col - 2 * EE;
          q_out[(size_t)row * SSS + s] = f2bf(val * gamma[s] + beta[s]);
          k_out[(size_t)row * SSS + s] = f2bf(val * gamma[SSS + s] + beta[SSS + s]);
        }
      }
    }
  }
}

// ---------------- attention: per block 64 rows x 512 e-cols, flash-style ----------------
__global__ __launch_bounds__(512) void attn_kernel(
    const short* __restrict__ q, const short* __restrict__ kk,
    const short* __restrict__ vT, const short* __restrict__ u,
    short* __restrict__ g)
{
  __shared__ __align__(16) short Sl[64][40];
  int bx = blockIdx.x;
  int b = bx >> 7, rem = bx & 127;
  int l0 = (rem >> 1) * 64, e0 = (rem & 1) * 512;
  int tid = threadIdx.x, wid = tid >> 6, lane = tid & 63;
  int rg = wid & 3, sg = wid >> 2;     // rg: row group (4), sg: m/e sub-group (2)
  int lr = lane & 15, lk = (lane >> 4) * 8;
  const short* qrow = q + (size_t)(b * LLL + l0 + rg * 16 + lr) * SSS;
  short8 qf[4];
  #pragma unroll
  for (int t = 0; t < 4; t++) qf[t] = *(const short8*)&qrow[t * 32 + lk];
  f32x4 acc[16];
  #pragma unroll
  for (int j = 0; j < 16; j++) acc[j] = (f32x4){0.f, 0.f, 0.f, 0.f};
  const short* kbase = kk + (size_t)b * LLL * SSS;
  const short* vbase = vT + (size_t)b * EE * LLL;
  #pragma unroll 1
  for (int m0 = 0; m0 < LLL; m0 += 32) {
    // S tile: rows rg*16.., m-cols sg*16..  (one 16x16 per wave)
    f32x4 sa = (f32x4){0.f, 0.f, 0.f, 0.f};
    const short* krow = kbase + (size_t)(m0 + sg * 16 + lr) * SSS;
    #pragma unroll
    for (int t = 0; t < 4; t++)
      sa = __builtin_amdgcn_mfma_f32_16x16x32_bf16(qf[t], *(const short8*)&krow[t * 32 + lk], sa, 0, 0, 0);
    #pragma unroll
    for (int r = 0; r < 4; r++) {
      float v = sa[r] * 0.08838834764831845f;   // 1/sqrt(128)
      v = fmaxf(v, 0.f);
      Sl[rg * 16 + (lane >> 4) * 4 + r][sg * 16 + lr] = f2bf(v * v);
    }
    __syncthreads();
    short8 af = *(const short8*)&Sl[rg * 16 + lr][lk];
    #pragma unroll
    for (int j = 0; j < 16; j++) {
      const short* vrow = vbase + (size_t)(e0 + sg * 256 + j * 16 + lr) * LLL + m0 + lk;
      acc[j] = __builtin_amdgcn_mfma_f32_16x16x32_bf16(af, *(const short8*)vrow, acc[j], 0, 0, 0);
    }
    __syncthreads();
  }
  #pragma unroll
  for (int j = 0; j < 16; j++) {
    int col = e0 + sg * 256 + j * 16 + lr;
    #pragma unroll
    for (int r = 0; r < 4; r++) {
      size_t row = (size_t)(b * LLL + l0 + rg * 16 + (lane >> 4) * 4 + r);
      size_t idx = row * EE + col;
      g[idx] = f2bf(bf2f(u[idx]) * acc[j][r]);
    }
  }
}

// ---------------- GEMM2: g[16384,1024] x W_outT[512,1024] + bias + residual ----------------
__global__ __launch_bounds__(256) void gemm_out_kernel(
    const short* __restrict__ A, const short* __restrict__ Bw,
    const float* __restrict__ b_out, const float* __restrict__ x,
    float* __restrict__ out)
{
  __shared__ __align__(16) short As[64][40];
  __shared__ __align__(16) short Bs[64][40];
  int m0 = blockIdx.x * 64, n0 = blockIdx.y * 64;
  int tid = threadIdx.x, wid = tid >> 6, lane = tid & 63;
  int wr = (wid >> 1) * 32, wc = (wid & 1) * 32;
  int srow = tid >> 2, scol = (tid & 3) * 8;
  int lr = lane & 15, lk = (lane >> 4) * 8;
  f32x4 acc[2][2];
  #pragma unroll
  for (int i = 0; i < 2; i++)
    #pragma unroll
    for (int j = 0; j < 2; j++) acc[i][j] = (f32x4){0.f, 0.f, 0.f, 0.f};
  for (int k0 = 0; k0 < EE; k0 += 32) {
    *(int4v*)&As[srow][scol] = *(const int4v*)&A[(size_t)(m0 + srow) * EE + k0 + scol];
    *(int4v*)&Bs[srow][scol] = *(const int4v*)&Bw[(size_t)(n0 + srow) * EE + k0 + scol];
    __syncthreads();
    short8 a0 = *(short8*)&As[wr + lr][lk];
    short8 a1 = *(short8*)&As[wr + 16 + lr][lk];
    short8 b0 = *(short8*)&Bs[wc + lr][lk];
    short8 b1 = *(short8*)&Bs[wc + 16 + lr][lk];
    acc[0][0] = __builtin_amdgcn_mfma_f32_16x16x32_bf16(a0, b0, acc[0][0], 0, 0, 0);
    acc[0][1] = __builtin_amdgcn_mfma_f32_16x16x32_bf16(a0, b1, acc[0][1], 0, 0, 0);
    acc[1][0] = __builtin_amdgcn_mfma_f32_16x16x32_bf16(a1, b0, acc[1][0], 0, 0, 0);
    acc[1][1] = __builtin_amdgcn_mfma_f32_16x16x32_bf16(a1, b1, acc[1][1], 0, 0, 0);
    __syncthreads();
  }
  #pragma unroll
  for (int i = 0; i < 2; i++) {
    #pragma unroll
    for (int j = 0; j < 2; j++) {
      int col = n0 + wc + j * 16 + lr;
      float bias = b_out[col];
      #pragma unroll
      for (int r = 0; r < 4; r++) {
        int row = m0 + wr + i * 16 + (lane >> 4) * 4 + r;
        size_t idx = (size_t)row * DIMD + col;
        out[idx] = acc[i][j][r] + bias + x[idx];
      }
    }
  }
}

extern "C" void kernel_launch(void* const* d_in, const int* in_sizes, int n_in,
                              void* d_out, int out_size, void* d_ws, size_t ws_size,
                              hipStream_t stream) {
  const float* x     = (const float*)d_in[0];
  const float* W_uv  = (const float*)d_in[1];
  const float* b_uv  = (const float*)d_in[2];
  const float* gamma = (const float*)d_in[3];
  const float* beta  = (const float*)d_in[4];
  const float* W_out = (const float*)d_in[5];
  const float* b_out = (const float*)d_in[6];
  const float* ln_w  = (const float*)d_in[7];
  const float* ln_b  = (const float*)d_in[8];
  float* out = (float*)d_out;

  char* ws = (char*)d_ws;
  short* W_uvT  = (short*)(ws);               // 2,228,224 B
  short* W_outT = (short*)(ws + 2228224);     // 1,048,576 B
  short* xn     = (short*)(ws + 3276800);     // 16,777,216 B
  short* qb     = (short*)(ws + 20054016);    // 4,194,304 B
  short* kb     = (short*)(ws + 24248320);    // 4,194,304 B
  short* ub     = (short*)(ws + 28442624);    // 33,554,432 B
  short* vTb    = (short*)(ws + 61997056);    // 33,554,432 B
  short* gb     = (short*)(ws + 95551488);    // 33,554,432 B  (total ~129.1 MB)

  prep_kernel<<<dim3((NUV * DIMD + 255) / 256), 256, 0, stream>>>(W_uv, W_out, W_uvT, W_outT);
  ln_kernel<<<dim3(NROW), 256, 0, stream>>>(x, ln_w, ln_b, xn);
  gemm_uv_kernel<<<dim3(NROW / 64, NUV / 64), 256, 0, stream>>>(xn, W_uvT, b_uv, gamma, beta, ub, vTb, qb, kb);
  attn_kernel<<<dim3(512), 512, 0, stream>>>(qb, kb, vTb, ub, gb);
  gemm_out_kernel<<<dim3(NROW / 64, DIMD / 64), 256, 0, stream>>>(gb, W_outT, b_out, x, out);
}

// Round 2
// 380.234 us; speedup vs baseline: 3.4048x; 3.4048x over previous
//
#include <hip/hip_runtime.h>

typedef __attribute__((ext_vector_type(8))) short short8;
typedef __attribute__((ext_vector_type(4))) float f32x4;

#define DIMD 512
#define EE 1024
#define SSS 128
#define LLL 4096
#define NROW 16384   // B*L
#define NUV 2176     // 2E+S

__device__ __forceinline__ short f2bf(float f) {
  union { float f; unsigned u; } un; un.f = f;
  unsigned r = un.u + 0x7FFFu + ((un.u >> 16) & 1u);
  return (short)(r >> 16);
}
__device__ __forceinline__ float bf2f(short s) {
  union { unsigned u; float f; } un;
  un.u = ((unsigned)(unsigned short)s) << 16;
  return un.f;
}
__device__ __forceinline__ float silu_f(float x) {
  return x / (1.0f + __expf(-x));
}

// async global->LDS, 16B per lane, wave-uniform LDS base + lane*16 auto
__device__ __forceinline__ void gld16(const short* g, short* l) {
  __builtin_amdgcn_global_load_lds(
      (const __attribute__((address_space(1))) unsigned int*)g,
      (__attribute__((address_space(3))) unsigned int*)l, 16, 0, 0);
}

// ---------------- prep: transpose+cast weights to bf16 ----------------
__global__ void prep_kernel(const float* __restrict__ W_uv, const float* __restrict__ W_out,
                            short* __restrict__ W_uvT, short* __restrict__ W_outT) {
  int i = blockIdx.x * blockDim.x + threadIdx.x;
  if (i < NUV * DIMD) {            // W_uvT[c][d] = W_uv[d][c]
    int c = i >> 9, d = i & (DIMD - 1);
    W_uvT[i] = f2bf(W_uv[(size_t)d * NUV + c]);
  }
  if (i < DIMD * EE) {             // W_outT[d][e] = W_out[e][d]
    int d = i >> 10, e = i & (EE - 1);
    W_outT[i] = f2bf(W_out[(size_t)e * DIMD + d]);
  }
}

// ---------------- layernorm -> xn bf16 ----------------
__global__ __launch_bounds__(256) void ln_kernel(const float* __restrict__ x,
    const float* __restrict__ w, const float* __restrict__ bb, short* __restrict__ xn) {
  int row = blockIdx.x;
  int tid = threadIdx.x;
  const float2* xr = (const float2*)(x + (size_t)row * DIMD);
  float2 v = xr[tid];
  float s = v.x + v.y, ss = v.x * v.x + v.y * v.y;
  #pragma unroll
  for (int off = 32; off >= 1; off >>= 1) {
    s += __shfl_down(s, off);
    ss += __shfl_down(ss, off);
  }
  __shared__ float ps[8];
  if ((tid & 63) == 0) { ps[tid >> 6] = s; ps[4 + (tid >> 6)] = ss; }
  __syncthreads();
  s = ps[0] + ps[1] + ps[2] + ps[3];
  ss = ps[4] + ps[5] + ps[6] + ps[7];
  float mu = s * (1.0f / DIMD);
  float var = ss * (1.0f / DIMD) - mu * mu;
  float inv = rsqrtf(var + 1e-5f);
  float2 wv = ((const float2*)w)[tid];
  float2 bv = ((const float2*)bb)[tid];
  short2 o;
  o.x = f2bf((v.x - mu) * inv * wv.x + bv.x);
  o.y = f2bf((v.y - mu) * inv * wv.y + bv.y);
  *(short2*)&xn[(size_t)row * DIMD + tid * 2] = o;
}

// ---------------- m97-style GEMM core: 128x128 tile, 4 waves, BK=32 ----------------
// A [M][lda] bf16 row-major (K-contig), B [N][ldb] bf16 row-major (K-contig).
// acc[m][n] per wave (wave grid 2x2, each wave 64x64). LDS: As=sm[0..4096), Bs=sm[4096..8192).
__device__ __forceinline__ void gemm_core(const short* __restrict__ A, const short* __restrict__ B,
                                          int lda, int ldb, int K, size_t m0, size_t n0,
                                          int tid, short* sm, f32x4 acc[4][4]) {
  short* As = sm;
  short* Bs = sm + 4096;
  int wid = tid >> 6, lane = tid & 63;
  int wr = (wid >> 1) * 64, wc = (wid & 1) * 64;
  int lr = lane & 15, lk = (lane >> 4) * 8;
  int r0 = tid >> 2, c0 = (tid & 3) * 8;       // staging: thread covers shorts [tid*8, tid*8+8)
  #pragma unroll
  for (int m = 0; m < 4; m++)
    #pragma unroll
    for (int n = 0; n < 4; n++) acc[m][n] = (f32x4){0.f, 0.f, 0.f, 0.f};
  for (int k0 = 0; k0 < K; k0 += 32) {
    gld16(&A[(m0 + r0) * lda + k0 + c0],      &As[wid * 512]);
    gld16(&A[(m0 + 64 + r0) * lda + k0 + c0], &As[2048 + wid * 512]);
    gld16(&B[(n0 + r0) * ldb + k0 + c0],      &Bs[wid * 512]);
    gld16(&B[(n0 + 64 + r0) * ldb + k0 + c0], &Bs[2048 + wid * 512]);
    __syncthreads();
    short8 af[4], bf[4];
    #pragma unroll
    for (int m = 0; m < 4; m++) af[m] = *(short8*)&As[(wr + m * 16 + lr) * 32 + lk];
    #pragma unroll
    for (int n = 0; n < 4; n++) bf[n] = *(short8*)&Bs[(wc + n * 16 + lr) * 32 + lk];
    #pragma unroll
    for (int m = 0; m < 4; m++)
      #pragma unroll
      for (int n = 0; n < 4; n++)
        acc[m][n] = __builtin_amdgcn_mfma_f32_16x16x32_bf16(af[m], bf[n], acc[m][n], 0, 0, 0);
    __syncthreads();
  }
}

// ---------------- GEMM1: xn x W_uvT + fused silu/affine epilogue ----------------
__global__ __launch_bounds__(256) void guv_kernel(
    const short* __restrict__ A, const short* __restrict__ Bw,
    const float* __restrict__ b_uv, const float* __restrict__ gamma, const float* __restrict__ beta,
    short* __restrict__ u_out, short* __restrict__ vT_out,
    short* __restrict__ q_out, short* __restrict__ k_out)
{
  __shared__ __align__(16) short sm[8192];
  int tid = threadIdx.x;
  size_t m0 = (size_t)blockIdx.x * 128, n0 = (size_t)blockIdx.y * 128;
  f32x4 acc[4][4];
  gemm_core(A, Bw, DIMD, DIMD, DIMD, m0, n0, tid, sm, acc);
  int wid = tid >> 6, lane = tid & 63;
  int wr = (wid >> 1) * 64, wc = (wid & 1) * 64;
  int lr = lane & 15;
  #pragma unroll
  for (int m = 0; m < 4; m++) {
    #pragma unroll
    for (int n = 0; n < 4; n++) {
      int col = (int)n0 + wc + n * 16 + lr;
      float bias = b_uv[col];
      int rowb = (int)m0 + wr + m * 16 + (lane >> 4) * 4;
      if (n0 < 1024) {                    // u tile
        #pragma unroll
        for (int r = 0; r < 4; r++)
          u_out[(size_t)(rowb + r) * EE + col] = f2bf(silu_f(acc[m][n][r] + bias));
      } else if (n0 < 2048) {             // v tile -> transposed store vT[b][e][l]
        int e = col - 1024, bb = rowb >> 12, lb = rowb & (LLL - 1);
        short4 o;
        o.x = f2bf(silu_f(acc[m][n][0] + bias));
        o.y = f2bf(silu_f(acc[m][n][1] + bias));
        o.z = f2bf(silu_f(acc[m][n][2] + bias));
        o.w = f2bf(silu_f(acc[m][n][3] + bias));
        *(short4*)&vT_out[((size_t)bb * EE + e) * LLL + lb] = o;
      } else {                            // q/k tile
        int s = col - 2048;
        float g0 = gamma[s], g1 = gamma[SSS + s], be0 = beta[s], be1 = beta[SSS + s];
        #pragma unroll
        for (int r = 0; r < 4; r++) {
          float val = acc[m][n][r] + bias;
          q_out[(size_t)(rowb + r) * SSS + s] = f2bf(val * g0 + be0);
          k_out[(size_t)(rowb + r) * SSS + s] = f2bf(val * g1 + be1);
        }
      }
    }
  }
}

// ---------------- QK^T -> P = relu(qk/sqrt(S))^2 (bf16) ----------------
__global__ __launch_bounds__(256) void gqk_kernel(
    const short* __restrict__ q, const short* __restrict__ k, short* __restrict__ P,
    long sq, long sk, long sp)
{
  __shared__ __align__(16) short sm[8192];
  int tid = threadIdx.x;
  const short* qz = q + (size_t)blockIdx.z * sq;
  const short* kz = k + (size_t)blockIdx.z * sk;
  short* Pz = P + (size_t)blockIdx.z * sp;
  size_t m0 = (size_t)blockIdx.x * 128, n0 = (size_t)blockIdx.y * 128;
  f32x4 acc[4][4];
  gemm_core(qz, kz, SSS, SSS, SSS, m0, n0, tid, sm, acc);
  int wid = tid >> 6, lane = tid & 63;
  int wr = (wid >> 1) * 64, wc = (wid & 1) * 64;
  int lr = lane & 15;
  const float scale = 0.08838834764831845f;  // 1/sqrt(128)
  #pragma unroll
  for (int m = 0; m < 4; m++) {
    #pragma unroll
    for (int n = 0; n < 4; n++) {
      int col = (int)n0 + wc + n * 16 + lr;
      int rowb = (int)m0 + wr + m * 16 + (lane >> 4) * 4;
      #pragma unroll
      for (int r = 0; r < 4; r++) {
        float v = fmaxf(acc[m][n][r] * scale, 0.f);
        Pz[(size_t)(rowb + r) * LLL + col] = f2bf(v * v);
      }
    }
  }
}

// ---------------- PV: P x vT, epilogue g = u * out ----------------
__global__ __launch_bounds__(256) void gpv_kernel(
    const short* __restrict__ P, const short* __restrict__ vT,
    const short* __restrict__ u, short* __restrict__ g,
    long sp, long sv, long su)
{
  __shared__ __align__(16) short sm[8192];
  int tid = threadIdx.x;
  const short* Pz = P + (size_t)blockIdx.z * sp;
  const short* vz = vT + (size_t)blockIdx.z * sv;
  const short* uz = u + (size_t)blockIdx.z * su;
  short* gz = g + (size_t)blockIdx.z * su;
  size_t m0 = (size_t)blockIdx.x * 128, n0 = (size_t)blockIdx.y * 128;
  f32x4 acc[4][4];
  gemm_core(Pz, vz, LLL, LLL, LLL, m0, n0, tid, sm, acc);
  int wid = tid >> 6, lane = tid & 63;
  int wr = (wid >> 1) * 64, wc = (wid & 1) * 64;
  int lr = lane & 15;
  #pragma unroll
  for (int m = 0; m < 4; m++) {
    #pragma unroll
    for (int n = 0; n < 4; n++) {
      int col = (int)n0 + wc + n * 16 + lr;
      int rowb = (int)m0 + wr + m * 16 + (lane >> 4) * 4;
      #pragma unroll
      for (int r = 0; r < 4; r++) {
        size_t idx = (size_t)(rowb + r) * EE + col;
        gz[idx] = f2bf(bf2f(uz[idx]) * acc[m][n][r]);
      }
    }
  }
}

// ---------------- GEMM2: g x W_outT + bias + residual (fp32 out) ----------------
__global__ __launch_bounds__(256) void gout_kernel(
    const short* __restrict__ A, const short* __restrict__ Bw,
    const float* __restrict__ b_out, const float* __restrict__ x,
    float* __restrict__ out)
{
  __shared__ __align__(16) short sm[8192];
  int tid = threadIdx.x;
  size_t m0 = (size_t)blockIdx.x * 128, n0 = (size_t)blockIdx.y * 128;
  f32x4 acc[4][4];
  gemm_core(A, Bw, EE, EE, EE, m0, n0, tid, sm, acc);
  int wid = tid >> 6, lane = tid & 63;
  int wr = (wid >> 1) * 64, wc = (wid & 1) * 64;
  int lr = lane & 15;
  #pragma unroll
  for (int m = 0; m < 4; m++) {
    #pragma unroll
    for (int n = 0; n < 4; n++) {
      int col = (int)n0 + wc + n * 16 + lr;
      float bias = b_out[col];
      int rowb = (int)m0 + wr + m * 16 + (lane >> 4) * 4;
      #pragma unroll
      for (int r = 0; r < 4; r++) {
        size_t idx = (size_t)(rowb + r) * DIMD + col;
        out[idx] = acc[m][n][r] + bias + x[idx];
      }
    }
  }
}

extern "C" void kernel_launch(void* const* d_in, const int* in_sizes, int n_in,
                              void* d_out, int out_size, void* d_ws, size_t ws_size,
                              hipStream_t stream) {
  const float* x     = (const float*)d_in[0];
  const float* W_uv  = (const float*)d_in[1];
  const float* b_uv  = (const float*)d_in[2];
  const float* gamma = (const float*)d_in[3];
  const float* beta  = (const float*)d_in[4];
  const float* W_out = (const float*)d_in[5];
  const float* b_out = (const float*)d_in[6];
  const float* ln_w  = (const float*)d_in[7];
  const float* ln_b  = (const float*)d_in[8];
  float* out = (float*)d_out;

  char* ws = (char*)d_ws;
  short* W_uvT  = (short*)(ws);               //  2,228,224
  short* W_outT = (short*)(ws + 2228224);     //  1,048,576
  short* xn     = (short*)(ws + 3276800);     // 16,777,216 (dead after guv; reusable)
  short* qb     = (short*)(ws + 20054016);    //  4,194,304
  short* kb     = (short*)(ws + 24248320);    //  4,194,304
  short* ub     = (short*)(ws + 28442624);    // 33,554,432
  short* vTb    = (short*)(ws + 61997056);    // 33,554,432
  short* gb     = (short*)(ws + 95551488);    // 33,554,432
  short* Pb     = (short*)(ws + 129105920);   // up to 134,217,728

  prep_kernel<<<dim3((NUV * DIMD + 255) / 256), 256, 0, stream>>>(W_uv, W_out, W_uvT, W_outT);
  ln_kernel<<<dim3(NROW), 256, 0, stream>>>(x, ln_w, ln_b, xn);
  guv_kernel<<<dim3(NROW / 128, NUV / 128), 256, 0, stream>>>(xn, W_uvT, b_uv, gamma, beta, ub, vTb, qb, kb);

  const long SQ = (long)LLL * SSS;            // q/k batch stride
  const long SP = (long)LLL * LLL;            // P batch stride
  const long SV = (long)EE * LLL;             // vT batch stride
  const long SU = (long)LLL * EE;             // u/g batch stride

  if (ws_size >= 129105920ull + 134217728ull) {
    // Tier A: full P, one launch pair, pv grid = 1024 blocks (4/CU)
    gqk_kernel<<<dim3(32, 32, 4), 256, 0, stream>>>(qb, kb, Pb, SQ, SQ, SP);
    gpv_kernel<<<dim3(32, 8, 4), 256, 0, stream>>>(Pb, vTb, ub, gb, SP, SV, SU);
  } else if (ws_size >= 129105920ull + 33554432ull) {
    // Tier M: per-batch P
    for (int b = 0; b < 4; b++) {
      gqk_kernel<<<dim3(32, 32, 1), 256, 0, stream>>>(qb + (size_t)b * SQ, kb + (size_t)b * SQ, Pb, 0, 0, 0);
      gpv_kernel<<<dim3(32, 8, 1), 256, 0, stream>>>(Pb, vTb + (size_t)b * SV, ub + (size_t)b * SU, gb + (size_t)b * SU, 0, 0, 0);
    }
  } else {
    // Tier B: P chunk (2048 rows) aliased over dead xn
    short* Pc = xn;
    for (int b = 0; b < 4; b++) {
      for (int h = 0; h < 2; h++) {
        size_t rowoff = (size_t)b * LLL + (size_t)h * 2048;
        gqk_kernel<<<dim3(16, 32, 1), 256, 0, stream>>>(qb + rowoff * SSS, kb + (size_t)b * SQ, Pc, 0, 0, 0);
        gpv_kernel<<<dim3(16, 8, 1), 256, 0, stream>>>(Pc, vTb + (size_t)b * SV, ub + rowoff * EE, gb + rowoff * EE, 0, 0, 0);
      }
    }
  }

  gout_kernel<<<dim3(NROW / 128, DIMD / 128), 256, 0, stream>>>(gb, W_outT, b_out, x, out);
}

// Round 3
// 331.682 us; speedup vs baseline: 3.9032x; 1.1464x over previous
//
#include <hip/hip_runtime.h>

typedef __attribute__((ext_vector_type(8))) short short8;
typedef __attribute__((ext_vector_type(4))) float f32x4;

#define DIMD 512
#define EE 1024
#define SSS 128
#define LLL 4096
#define NROW 16384   // B*L
#define NUV 2176     // 2E+S

__device__ __forceinline__ short f2bf(float f) {
  union { float f; unsigned u; } un; un.f = f;
  unsigned r = un.u + 0x7FFFu + ((un.u >> 16) & 1u);
  return (short)(r >> 16);
}
__device__ __forceinline__ float bf2f(short s) {
  union { unsigned u; float f; } un;
  un.u = ((unsigned)(unsigned short)s) << 16;
  return un.f;
}
__device__ __forceinline__ float silu_f(float x) {
  return x / (1.0f + __expf(-x));
}

__device__ __forceinline__ void gld16(const short* g, short* l) {
  __builtin_amdgcn_global_load_lds(
      (const __attribute__((address_space(1))) unsigned int*)g,
      (__attribute__((address_space(3))) unsigned int*)l, 16, 0, 0);
}

#define MFMA16(a, b, c) c = __builtin_amdgcn_mfma_f32_16x16x32_bf16(a, b, c, 0, 0, 0)
#define SBAR() asm volatile("s_barrier" ::: "memory")

// ---------------- prep: transpose+cast weights to bf16 ----------------
__global__ void prep_kernel(const float* __restrict__ W_uv, const float* __restrict__ W_out,
                            short* __restrict__ W_uvT, short* __restrict__ W_outT) {
  int i = blockIdx.x * blockDim.x + threadIdx.x;
  if (i < NUV * DIMD) {
    int c = i >> 9, d = i & (DIMD - 1);
    W_uvT[i] = f2bf(W_uv[(size_t)d * NUV + c]);
  }
  if (i < DIMD * EE) {
    int d = i >> 10, e = i & (EE - 1);
    W_outT[i] = f2bf(W_out[(size_t)e * DIMD + d]);
  }
}

// ---------------- layernorm -> xn bf16 ----------------
__global__ __launch_bounds__(256) void ln_kernel(const float* __restrict__ x,
    const float* __restrict__ w, const float* __restrict__ bb, short* __restrict__ xn) {
  int row = blockIdx.x;
  int tid = threadIdx.x;
  const float2* xr = (const float2*)(x + (size_t)row * DIMD);
  float2 v = xr[tid];
  float s = v.x + v.y, ss = v.x * v.x + v.y * v.y;
  #pragma unroll
  for (int off = 32; off >= 1; off >>= 1) {
    s += __shfl_down(s, off);
    ss += __shfl_down(ss, off);
  }
  __shared__ float ps[8];
  if ((tid & 63) == 0) { ps[tid >> 6] = s; ps[4 + (tid >> 6)] = ss; }
  __syncthreads();
  s = ps[0] + ps[1] + ps[2] + ps[3];
  ss = ps[4] + ps[5] + ps[6] + ps[7];
  float mu = s * (1.0f / DIMD);
  float var = ss * (1.0f / DIMD) - mu * mu;
  float inv = rsqrtf(var + 1e-5f);
  float2 wv = ((const float2*)w)[tid];
  float2 bv = ((const float2*)bb)[tid];
  short2 o;
  o.x = f2bf((v.x - mu) * inv * wv.x + bv.x);
  o.y = f2bf((v.y - mu) * inv * wv.y + bv.y);
  *(short2*)&xn[(size_t)row * DIMD + tid * 2] = o;
}

// ---------------- m97-style GEMM core: 128x128 tile, 4 waves, BK=32 ----------------
__device__ __forceinline__ void gemm_core(const short* __restrict__ A, const short* __restrict__ B,
                                          int lda, int ldb, int K, size_t m0, size_t n0,
                                          int tid, short* sm, f32x4 acc[4][4]) {
  short* As = sm;
  short* Bs = sm + 4096;
  int wid = tid >> 6, lane = tid & 63;
  int wr = (wid >> 1) * 64, wc = (wid & 1) * 64;
  int lr = lane & 15, lk = (lane >> 4) * 8;
  int r0 = tid >> 2, c0 = (tid & 3) * 8;
  #pragma unroll
  for (int m = 0; m < 4; m++)
    #pragma unroll
    for (int n = 0; n < 4; n++) acc[m][n] = (f32x4){0.f, 0.f, 0.f, 0.f};
  for (int k0 = 0; k0 < K; k0 += 32) {
    gld16(&A[(m0 + r0) * lda + k0 + c0],      &As[wid * 512]);
    gld16(&A[(m0 + 64 + r0) * lda + k0 + c0], &As[2048 + wid * 512]);
    gld16(&B[(n0 + r0) * ldb + k0 + c0],      &Bs[wid * 512]);
    gld16(&B[(n0 + 64 + r0) * ldb + k0 + c0], &Bs[2048 + wid * 512]);
    __syncthreads();
    short8 af[4], bf[4];
    #pragma unroll
    for (int m = 0; m < 4; m++) af[m] = *(short8*)&As[(wr + m * 16 + lr) * 32 + lk];
    #pragma unroll
    for (int n = 0; n < 4; n++) bf[n] = *(short8*)&Bs[(wc + n * 16 + lr) * 32 + lk];
    #pragma unroll
    for (int m = 0; m < 4; m++)
      #pragma unroll
      for (int n = 0; n < 4; n++)
        MFMA16(af[m], bf[n], acc[m][n]);
    __syncthreads();
  }
}

// ---------------- GEMM1: xn x W_uvT + fused silu/affine epilogue ----------------
__global__ __launch_bounds__(256) void guv_kernel(
    const short* __restrict__ A, const short* __restrict__ Bw,
    const float* __restrict__ b_uv, const float* __restrict__ gamma, const float* __restrict__ beta,
    short* __restrict__ u_out, short* __restrict__ vT_out,
    short* __restrict__ q_out, short* __restrict__ k_out)
{
  __shared__ __align__(16) short sm[8192];
  int tid = threadIdx.x;
  size_t m0 = (size_t)blockIdx.x * 128, n0 = (size_t)blockIdx.y * 128;
  f32x4 acc[4][4];
  gemm_core(A, Bw, DIMD, DIMD, DIMD, m0, n0, tid, sm, acc);
  int wid = tid >> 6, lane = tid & 63;
  int wr = (wid >> 1) * 64, wc = (wid & 1) * 64;
  int lr = lane & 15;
  #pragma unroll
  for (int m = 0; m < 4; m++) {
    #pragma unroll
    for (int n = 0; n < 4; n++) {
      int col = (int)n0 + wc + n * 16 + lr;
      float bias = b_uv[col];
      int rowb = (int)m0 + wr + m * 16 + (lane >> 4) * 4;
      if (n0 < 1024) {
        #pragma unroll
        for (int r = 0; r < 4; r++)
          u_out[(size_t)(rowb + r) * EE + col] = f2bf(silu_f(acc[m][n][r] + bias));
      } else if (n0 < 2048) {
        int e = col - 1024, bb = rowb >> 12, lb = rowb & (LLL - 1);
        short4 o;
        o.x = f2bf(silu_f(acc[m][n][0] + bias));
        o.y = f2bf(silu_f(acc[m][n][1] + bias));
        o.z = f2bf(silu_f(acc[m][n][2] + bias));
        o.w = f2bf(silu_f(acc[m][n][3] + bias));
        *(short4*)&vT_out[((size_t)bb * EE + e) * LLL + lb] = o;
      } else {
        int s = col - 2048;
        float g0 = gamma[s], g1 = gamma[SSS + s], be0 = beta[s], be1 = beta[SSS + s];
        #pragma unroll
        for (int r = 0; r < 4; r++) {
          float val = acc[m][n][r] + bias;
          q_out[(size_t)(rowb + r) * SSS + s] = f2bf(val * g0 + be0);
          k_out[(size_t)(rowb + r) * SSS + s] = f2bf(val * g1 + be1);
        }
      }
    }
  }
}

// ---------------- QK^T -> P = relu(qk/sqrt(S))^2 (bf16) ----------------
__global__ __launch_bounds__(256) void gqk_kernel(
    const short* __restrict__ q, const short* __restrict__ k, short* __restrict__ P,
    long sq, long sk, long sp)
{
  __shared__ __align__(16) short sm[8192];
  int tid = threadIdx.x;
  const short* qz = q + (size_t)blockIdx.z * sq;
  const short* kz = k + (size_t)blockIdx.z * sk;
  short* Pz = P + (size_t)blockIdx.z * sp;
  size_t m0 = (size_t)blockIdx.x * 128, n0 = (size_t)blockIdx.y * 128;
  f32x4 acc[4][4];
  gemm_core(qz, kz, SSS, SSS, SSS, m0, n0, tid, sm, acc);
  int wid = tid >> 6, lane = tid & 63;
  int wr = (wid >> 1) * 64, wc = (wid & 1) * 64;
  int lr = lane & 15;
  const float scale = 0.08838834764831845f;
  #pragma unroll
  for (int m = 0; m < 4; m++) {
    #pragma unroll
    for (int n = 0; n < 4; n++) {
      int col = (int)n0 + wc + n * 16 + lr;
      int rowb = (int)m0 + wr + m * 16 + (lane >> 4) * 4;
      #pragma unroll
      for (int r = 0; r < 4; r++) {
        float v = fmaxf(acc[m][n][r] * scale, 0.f);
        Pz[(size_t)(rowb + r) * LLL + col] = f2bf(v * v);
      }
    }
  }
}

// ---------------- legacy PV (fallback tiers): m97 core ----------------
__global__ __launch_bounds__(256) void gpv_kernel(
    const short* __restrict__ P, const short* __restrict__ vT,
    const short* __restrict__ u, short* __restrict__ g,
    long sp, long sv, long su)
{
  __shared__ __align__(16) short sm[8192];
  int tid = threadIdx.x;
  const short* Pz = P + (size_t)blockIdx.z * sp;
  const short* vz = vT + (size_t)blockIdx.z * sv;
  const short* uz = u + (size_t)blockIdx.z * su;
  short* gz = g + (size_t)blockIdx.z * su;
  size_t m0 = (size_t)blockIdx.x * 128, n0 = (size_t)blockIdx.y * 128;
  f32x4 acc[4][4];
  gemm_core(Pz, vz, LLL, LLL, LLL, m0, n0, tid, sm, acc);
  int wid = tid >> 6, lane = tid & 63;
  int wr = (wid >> 1) * 64, wc = (wid & 1) * 64;
  int lr = lane & 15;
  #pragma unroll
  for (int m = 0; m < 4; m++) {
    #pragma unroll
    for (int n = 0; n < 4; n++) {
      int col = (int)n0 + wc + n * 16 + lr;
      int rowb = (int)m0 + wr + m * 16 + (lane >> 4) * 4;
      #pragma unroll
      for (int r = 0; r < 4; r++) {
        size_t idx = (size_t)(rowb + r) * EE + col;
        gz[idx] = f2bf(bf2f(uz[idx]) * acc[m][n][r]);
      }
    }
  }
}

// ---------------- PV, 256x256 8-phase pipeline (T2+T3+T4+T5) ----------------
// C[m0:m0+256][n0:n0+256] = P[4096x4096] x vT[1024x4096]^T per batch.
// 8 waves (2M x 4N), BK=64, 128 KiB LDS (2 dbuf x (A:32KB + B:32KB)).
// LDS half-tile [128][64] shorts; swizzle: col ^= (row&3)<<4, applied on the
// pre-swizzled global source (write side) and on ds_read (read side).
__global__ __launch_bounds__(512, 2) void gpv8_kernel(
    const short* __restrict__ Pg, const short* __restrict__ vTg,
    const short* __restrict__ ug, short* __restrict__ gg)
{
  extern __shared__ __align__(16) short sm[];
  const int b = blockIdx.z;
  const size_t m0 = (size_t)blockIdx.x * 256;
  const size_t n0 = (size_t)blockIdx.y * 256;
  const short* A  = Pg  + (size_t)b * LLL * LLL;     // [4096][4096]
  const short* Bv = vTg + (size_t)b * EE * LLL;      // [1024][4096]
  const int tid = threadIdx.x, w = tid >> 6, l = tid & 63;
  const int lr = l & 15;
  // staging source pre-swizzle: thread covers row (w*8 + l>>3) of a 64-row unit
  const int colsrc = ((l & 7) * 8) ^ (((l >> 3) & 3) << 4);
  const short* srcA = A  + (m0 + w * 8 + (l >> 3)) * LLL + colsrc;
  const short* srcB = Bv + (n0 + w * 8 + (l >> 3)) * LLL + colsrc;
  // ds_read swizzled k-columns (row&3 == lr&3)
  const int csw0 = ((l >> 4) * 8) ^ ((l & 3) << 4);
  const int csw1 = (32 + (l >> 4) * 8) ^ ((l & 3) << 4);
  const int AhalfOff = (w >> 2) * 8192 + lr * 64;
  const int BhalfOff = 16384 + ((w & 3) >> 1) * 8192 + ((w & 1) * 64 + lr) * 64;

  #define STA8(bf_, h_, q_, kt_) gld16(srcA + ((h_) * 128 + (q_) * 64) * (size_t)LLL + (kt_) * 64, \
                                       &sm[(bf_) * 32768 + (h_) * 8192 + (q_) * 4096 + w * 512])
  #define STB8(bf_, h_, q_, kt_) gld16(srcB + ((h_) * 128 + (q_) * 64) * (size_t)LLL + (kt_) * 64, \
                                       &sm[(bf_) * 32768 + 16384 + (h_) * 8192 + (q_) * 4096 + w * 512])

  f32x4 acc[8][4];
  #pragma unroll
  for (int m = 0; m < 8; m++)
    #pragma unroll
    for (int n = 0; n < 4; n++) acc[m][n] = (f32x4){0.f, 0.f, 0.f, 0.f};
  short8 Af[4][2], Bf0[2][2], Bf1[2][2];

  // prologue: tile0 fully (8 units), tile1 A-lows (2 units)
  STA8(0, 0, 0, 0); STA8(0, 1, 0, 0); STA8(0, 0, 1, 0); STA8(0, 1, 1, 0);
  STB8(0, 0, 0, 0); STB8(0, 0, 1, 0); STB8(0, 1, 0, 0); STB8(0, 1, 1, 0);
  STA8(1, 0, 0, 1); STA8(1, 1, 0, 1);
  asm volatile("s_waitcnt vmcnt(2)" ::: "memory");
  SBAR();
  __builtin_amdgcn_sched_barrier(0);

  const int T = LLL / 64;   // 64 K-tiles
  for (int t = 0; t < T; ++t) {
    const int buf = t & 1, nb = buf ^ 1;
    short* Ab = sm + buf * 32768 + AhalfOff;
    short* Bb = sm + buf * 32768 + BhalfOff;
    // ---- q1: quadrant (mh0, nh0)
    if (t + 1 < T) STA8(nb, 0, 1, t + 1);
    #pragma unroll
    for (int i = 0; i < 4; ++i) {
      Af[i][0] = *(const short8*)&Ab[i * 1024 + csw0];
      Af[i][1] = *(const short8*)&Ab[i * 1024 + csw1];
    }
    #pragma unroll
    for (int j = 0; j < 2; ++j) {
      Bf0[j][0] = *(const short8*)&Bb[j * 1024 + csw0];
      Bf0[j][1] = *(const short8*)&Bb[j * 1024 + csw1];
    }
    SBAR();
    __builtin_amdgcn_s_setprio(1);
    #pragma unroll
    for (int i = 0; i < 4; ++i)
      #pragma unroll
      for (int j = 0; j < 2; ++j) {
        MFMA16(Af[i][0], Bf0[j][0], acc[i][j]);
        MFMA16(Af[i][1], Bf0[j][1], acc[i][j]);
      }
    __builtin_amdgcn_s_setprio(0);
    SBAR();
    // ---- q2: quadrant (mh0, nh1)
    if (t + 1 < T) STA8(nb, 1, 1, t + 1);
    #pragma unroll
    for (int j = 0; j < 2; ++j) {
      Bf1[j][0] = *(const short8*)&Bb[2048 + j * 1024 + csw0];
      Bf1[j][1] = *(const short8*)&Bb[2048 + j * 1024 + csw1];
    }
    SBAR();
    __builtin_amdgcn_s_setprio(1);
    #pragma unroll
    for (int i = 0; i < 4; ++i)
      #pragma unroll
      for (int j = 0; j < 2; ++j) {
        MFMA16(Af[i][0], Bf1[j][0], acc[i][2 + j]);
        MFMA16(Af[i][1], Bf1[j][1], acc[i][2 + j]);
      }
    __builtin_amdgcn_s_setprio(0);
    SBAR();
    // ---- q3: quadrant (mh1, nh1)
    if (t + 1 < T) { STB8(nb, 0, 0, t + 1); STB8(nb, 0, 1, t + 1); }
    #pragma unroll
    for (int i = 0; i < 4; ++i) {
      Af[i][0] = *(const short8*)&Ab[4096 + i * 1024 + csw0];
      Af[i][1] = *(const short8*)&Ab[4096 + i * 1024 + csw1];
    }
    SBAR();
    __builtin_amdgcn_s_setprio(1);
    #pragma unroll
    for (int i = 0; i < 4; ++i)
      #pragma unroll
      for (int j = 0; j < 2; ++j) {
        MFMA16(Af[i][0], Bf1[j][0], acc[4 + i][2 + j]);
        MFMA16(Af[i][1], Bf1[j][1], acc[4 + i][2 + j]);
      }
    __builtin_amdgcn_s_setprio(0);
    SBAR();
    // ---- q4: quadrant (mh1, nh0) + tile boundary
    if (t + 1 < T) { STB8(nb, 1, 0, t + 1); STB8(nb, 1, 1, t + 1); }
    if (t + 2 < T) { STA8(buf, 0, 0, t + 2); STA8(buf, 1, 0, t + 2); }
    SBAR();
    __builtin_amdgcn_s_setprio(1);
    #pragma unroll
    for (int i = 0; i < 4; ++i)
      #pragma unroll
      for (int j = 0; j < 2; ++j) {
        MFMA16(Af[i][0], Bf0[j][0], acc[4 + i][j]);
        MFMA16(Af[i][1], Bf0[j][1], acc[4 + i][j]);
      }
    __builtin_amdgcn_s_setprio(0);
    if (t < T - 2) {
      asm volatile("s_waitcnt vmcnt(2)" ::: "memory");
      SBAR();
      __builtin_amdgcn_sched_barrier(0);
    } else if (t == T - 2) {
      asm volatile("s_waitcnt vmcnt(0)" ::: "memory");
      SBAR();
      __builtin_amdgcn_sched_barrier(0);
    }
  }
  // epilogue: g = u * acc
  const short* ub_ = ug + (size_t)b * LLL * EE;
  short* gb_ = gg + (size_t)b * LLL * EE;
  const int rowb0 = (int)m0 + (w >> 2) * 128 + (l >> 4) * 4;
  const int colb0 = (int)n0 + (w & 3) * 64 + lr;
  #pragma unroll
  for (int mf = 0; mf < 8; ++mf) {
    #pragma unroll
    for (int nf = 0; nf < 4; ++nf) {
      int col = colb0 + nf * 16;
      #pragma unroll
      for (int r = 0; r < 4; ++r) {
        size_t idx = (size_t)(rowb0 + mf * 16 + r) * EE + col;
        gb_[idx] = f2bf(bf2f(ub_[idx]) * acc[mf][nf][r]);
      }
    }
  }
  #undef STA8
  #undef STB8
}

// ---------------- GEMM2: g x W_outT + bias + residual (fp32 out) ----------------
__global__ __launch_bounds__(256) void gout_kernel(
    const short* __restrict__ A, const short* __restrict__ Bw,
    const float* __restrict__ b_out, const float* __restrict__ x,
    float* __restrict__ out)
{
  __shared__ __align__(16) short sm[8192];
  int tid = threadIdx.x;
  size_t m0 = (size_t)blockIdx.x * 128, n0 = (size_t)blockIdx.y * 128;
  f32x4 acc[4][4];
  gemm_core(A, Bw, EE, EE, EE, m0, n0, tid, sm, acc);
  int wid = tid >> 6, lane = tid & 63;
  int wr = (wid >> 1) * 64, wc = (wid & 1) * 64;
  int lr = lane & 15;
  #pragma unroll
  for (int m = 0; m < 4; m++) {
    #pragma unroll
    for (int n = 0; n < 4; n++) {
      int col = (int)n0 + wc + n * 16 + lr;
      float bias = b_out[col];
      int rowb = (int)m0 + wr + m * 16 + (lane >> 4) * 4;
      #pragma unroll
      for (int r = 0; r < 4; r++) {
        size_t idx = (size_t)(rowb + r) * DIMD + col;
        out[idx] = acc[m][n][r] + bias + x[idx];
      }
    }
  }
}

extern "C" void kernel_launch(void* const* d_in, const int* in_sizes, int n_in,
                              void* d_out, int out_size, void* d_ws, size_t ws_size,
                              hipStream_t stream) {
  const float* x     = (const float*)d_in[0];
  const float* W_uv  = (const float*)d_in[1];
  const float* b_uv  = (const float*)d_in[2];
  const float* gamma = (const float*)d_in[3];
  const float* beta  = (const float*)d_in[4];
  const float* W_out = (const float*)d_in[5];
  const float* b_out = (const float*)d_in[6];
  const float* ln_w  = (const float*)d_in[7];
  const float* ln_b  = (const float*)d_in[8];
  float* out = (float*)d_out;

  char* ws = (char*)d_ws;
  short* W_uvT  = (short*)(ws);
  short* W_outT = (short*)(ws + 2228224);
  short* xn     = (short*)(ws + 3276800);
  short* qb     = (short*)(ws + 20054016);
  short* kb     = (short*)(ws + 24248320);
  short* ub     = (short*)(ws + 28442624);
  short* vTb    = (short*)(ws + 61997056);
  short* gb     = (short*)(ws + 95551488);
  short* Pb     = (short*)(ws + 129105920);

  prep_kernel<<<dim3((NUV * DIMD + 255) / 256), 256, 0, stream>>>(W_uv, W_out, W_uvT, W_outT);
  ln_kernel<<<dim3(NROW), 256, 0, stream>>>(x, ln_w, ln_b, xn);
  guv_kernel<<<dim3(NROW / 128, NUV / 128), 256, 0, stream>>>(xn, W_uvT, b_uv, gamma, beta, ub, vTb, qb, kb);

  const long SQ = (long)LLL * SSS;
  const long SP = (long)LLL * LLL;
  const long SV = (long)EE * LLL;
  const long SU = (long)LLL * EE;

  if (ws_size >= 129105920ull + 134217728ull) {
    gqk_kernel<<<dim3(32, 32, 4), 256, 0, stream>>>(qb, kb, Pb, SQ, SQ, SP);
    gpv8_kernel<<<dim3(16, 4, 4), 512, 131072, stream>>>(Pb, vTb, ub, gb);
  } else if (ws_size >= 129105920ull + 33554432ull) {
    for (int b = 0; b < 4; b++) {
      gqk_kernel<<<dim3(32, 32, 1), 256, 0, stream>>>(qb + (size_t)b * SQ, kb + (size_t)b * SQ, Pb, 0, 0, 0);
      gpv_kernel<<<dim3(32, 8, 1), 256, 0, stream>>>(Pb, vTb + (size_t)b * SV, ub + (size_t)b * SU, gb + (size_t)b * SU, 0, 0, 0);
    }
  } else {
    short* Pc = xn;
    for (int b = 0; b < 4; b++) {
      for (int h = 0; h < 2; h++) {
        size_t rowoff = (size_t)b * LLL + (size_t)h * 2048;
        gqk_kernel<<<dim3(16, 32, 1), 256, 0, stream>>>(qb + rowoff * SSS, kb + (size_t)b * SQ, Pc, 0, 0, 0);
        gpv_kernel<<<dim3(16, 8, 1), 256, 0, stream>>>(Pc, vTb + (size_t)b * SV, ub + rowoff * EE, gb + rowoff * EE, 0, 0, 0);
      }
    }
  }

  gout_kernel<<<dim3(NROW / 128, DIMD / 128), 256, 0, stream>>>(gb, W_outT, b_out, x, out);
}

// Round 4
// 318.692 us; speedup vs baseline: 4.0622x; 1.0408x over previous
//
#include <hip/hip_runtime.h>

typedef __attribute__((ext_vector_type(8))) short short8;
typedef __attribute__((ext_vector_type(4))) float f32x4;

#define DIMD 512
#define EE 1024
#define SSS 128
#define LLL 4096
#define NROW 16384   // B*L
#define NUV 2176     // 2E+S

__device__ __forceinline__ short f2bf(float f) {
  union { float f; unsigned u; } un; un.f = f;
  unsigned r = un.u + 0x7FFFu + ((un.u >> 16) & 1u);
  return (short)(r >> 16);
}
__device__ __forceinline__ float bf2f(short s) {
  union { unsigned u; float f; } un;
  un.u = ((unsigned)(unsigned short)s) << 16;
  return un.f;
}
__device__ __forceinline__ float silu_f(float x) {
  return x / (1.0f + __expf(-x));
}

__device__ __forceinline__ void gld16(const short* g, short* l) {
  __builtin_amdgcn_global_load_lds(
      (const __attribute__((address_space(1))) unsigned int*)g,
      (__attribute__((address_space(3))) unsigned int*)l, 16, 0, 0);
}

#define MFMA16(a, b, c) c = __builtin_amdgcn_mfma_f32_16x16x32_bf16(a, b, c, 0, 0, 0)
#define SBAR() asm volatile("s_barrier" ::: "memory")

// ---------------- prep: transpose+cast weights to bf16 ----------------
__global__ void prep_kernel(const float* __restrict__ W_uv, const float* __restrict__ W_out,
                            short* __restrict__ W_uvT, short* __restrict__ W_outT) {
  int i = blockIdx.x * blockDim.x + threadIdx.x;
  if (i < NUV * DIMD) {
    int c = i >> 9, d = i & (DIMD - 1);
    W_uvT[i] = f2bf(W_uv[(size_t)d * NUV + c]);
  }
  if (i < DIMD * EE) {
    int d = i >> 10, e = i & (EE - 1);
    W_outT[i] = f2bf(W_out[(size_t)e * DIMD + d]);
  }
}

// ---------------- layernorm -> xn bf16 ----------------
__global__ __launch_bounds__(256) void ln_kernel(const float* __restrict__ x,
    const float* __restrict__ w, const float* __restrict__ bb, short* __restrict__ xn) {
  int row = blockIdx.x;
  int tid = threadIdx.x;
  const float2* xr = (const float2*)(x + (size_t)row * DIMD);
  float2 v = xr[tid];
  float s = v.x + v.y, ss = v.x * v.x + v.y * v.y;
  #pragma unroll
  for (int off = 32; off >= 1; off >>= 1) {
    s += __shfl_down(s, off);
    ss += __shfl_down(ss, off);
  }
  __shared__ float ps[8];
  if ((tid & 63) == 0) { ps[tid >> 6] = s; ps[4 + (tid >> 6)] = ss; }
  __syncthreads();
  s = ps[0] + ps[1] + ps[2] + ps[3];
  ss = ps[4] + ps[5] + ps[6] + ps[7];
  float mu = s * (1.0f / DIMD);
  float var = ss * (1.0f / DIMD) - mu * mu;
  float inv = rsqrtf(var + 1e-5f);
  float2 wv = ((const float2*)w)[tid];
  float2 bv = ((const float2*)bb)[tid];
  short2 o;
  o.x = f2bf((v.x - mu) * inv * wv.x + bv.x);
  o.y = f2bf((v.y - mu) * inv * wv.y + bv.y);
  *(short2*)&xn[(size_t)row * DIMD + tid * 2] = o;
}

// ---------------- m97-style GEMM core: 128x128 tile, 4 waves, BK=32 ----------------
__device__ __forceinline__ void gemm_core(const short* __restrict__ A, const short* __restrict__ B,
                                          int lda, int ldb, int K, size_t m0, size_t n0,
                                          int tid, short* sm, f32x4 acc[4][4]) {
  short* As = sm;
  short* Bs = sm + 4096;
  int wid = tid >> 6, lane = tid & 63;
  int wr = (wid >> 1) * 64, wc = (wid & 1) * 64;
  int lr = lane & 15, lk = (lane >> 4) * 8;
  int r0 = tid >> 2, c0 = (tid & 3) * 8;
  #pragma unroll
  for (int m = 0; m < 4; m++)
    #pragma unroll
    for (int n = 0; n < 4; n++) acc[m][n] = (f32x4){0.f, 0.f, 0.f, 0.f};
  for (int k0 = 0; k0 < K; k0 += 32) {
    gld16(&A[(m0 + r0) * lda + k0 + c0],      &As[wid * 512]);
    gld16(&A[(m0 + 64 + r0) * lda + k0 + c0], &As[2048 + wid * 512]);
    gld16(&B[(n0 + r0) * ldb + k0 + c0],      &Bs[wid * 512]);
    gld16(&B[(n0 + 64 + r0) * ldb + k0 + c0], &Bs[2048 + wid * 512]);
    __syncthreads();
    short8 af[4], bf[4];
    #pragma unroll
    for (int m = 0; m < 4; m++) af[m] = *(short8*)&As[(wr + m * 16 + lr) * 32 + lk];
    #pragma unroll
    for (int n = 0; n < 4; n++) bf[n] = *(short8*)&Bs[(wc + n * 16 + lr) * 32 + lk];
    #pragma unroll
    for (int m = 0; m < 4; m++)
      #pragma unroll
      for (int n = 0; n < 4; n++)
        MFMA16(af[m], bf[n], acc[m][n]);
    __syncthreads();
  }
}

// ---------------- GEMM1: xn x W_uvT + fused silu/affine epilogue ----------------
__global__ __launch_bounds__(256) void guv_kernel(
    const short* __restrict__ A, const short* __restrict__ Bw,
    const float* __restrict__ b_uv, const float* __restrict__ gamma, const float* __restrict__ beta,
    short* __restrict__ u_out, short* __restrict__ vT_out,
    short* __restrict__ q_out, short* __restrict__ k_out)
{
  __shared__ __align__(16) short sm[8192];
  int tid = threadIdx.x;
  size_t m0 = (size_t)blockIdx.x * 128, n0 = (size_t)blockIdx.y * 128;
  f32x4 acc[4][4];
  gemm_core(A, Bw, DIMD, DIMD, DIMD, m0, n0, tid, sm, acc);
  int wid = tid >> 6, lane = tid & 63;
  int wr = (wid >> 1) * 64, wc = (wid & 1) * 64;
  int lr = lane & 15;
  #pragma unroll
  for (int m = 0; m < 4; m++) {
    #pragma unroll
    for (int n = 0; n < 4; n++) {
      int col = (int)n0 + wc + n * 16 + lr;
      float bias = b_uv[col];
      int rowb = (int)m0 + wr + m * 16 + (lane >> 4) * 4;
      if (n0 < 1024) {
        #pragma unroll
        for (int r = 0; r < 4; r++)
          u_out[(size_t)(rowb + r) * EE + col] = f2bf(silu_f(acc[m][n][r] + bias));
      } else if (n0 < 2048) {
        int e = col - 1024, bb = rowb >> 12, lb = rowb & (LLL - 1);
        short4 o;
        o.x = f2bf(silu_f(acc[m][n][0] + bias));
        o.y = f2bf(silu_f(acc[m][n][1] + bias));
        o.z = f2bf(silu_f(acc[m][n][2] + bias));
        o.w = f2bf(silu_f(acc[m][n][3] + bias));
        *(short4*)&vT_out[((size_t)bb * EE + e) * LLL + lb] = o;
      } else {
        int s = col - 2048;
        float g0 = gamma[s], g1 = gamma[SSS + s], be0 = beta[s], be1 = beta[SSS + s];
        #pragma unroll
        for (int r = 0; r < 4; r++) {
          float val = acc[m][n][r] + bias;
          q_out[(size_t)(rowb + r) * SSS + s] = f2bf(val * g0 + be0);
          k_out[(size_t)(rowb + r) * SSS + s] = f2bf(val * g1 + be1);
        }
      }
    }
  }
}

// ---------------- QK^T -> P = relu(qk/sqrt(S))^2 (bf16) ----------------
__global__ __launch_bounds__(256) void gqk_kernel(
    const short* __restrict__ q, const short* __restrict__ k, short* __restrict__ P,
    long sq, long sk, long sp)
{
  __shared__ __align__(16) short sm[8192];
  int tid = threadIdx.x;
  const short* qz = q + (size_t)blockIdx.z * sq;
  const short* kz = k + (size_t)blockIdx.z * sk;
  short* Pz = P + (size_t)blockIdx.z * sp;
  size_t m0 = (size_t)blockIdx.x * 128, n0 = (size_t)blockIdx.y * 128;
  f32x4 acc[4][4];
  gemm_core(qz, kz, SSS, SSS, SSS, m0, n0, tid, sm, acc);
  int wid = tid >> 6, lane = tid & 63;
  int wr = (wid >> 1) * 64, wc = (wid & 1) * 64;
  int lr = lane & 15;
  const float scale = 0.08838834764831845f;
  #pragma unroll
  for (int m = 0; m < 4; m++) {
    #pragma unroll
    for (int n = 0; n < 4; n++) {
      int col = (int)n0 + wc + n * 16 + lr;
      int rowb = (int)m0 + wr + m * 16 + (lane >> 4) * 4;
      #pragma unroll
      for (int r = 0; r < 4; r++) {
        float v = fmaxf(acc[m][n][r] * scale, 0.f);
        Pz[(size_t)(rowb + r) * LLL + col] = f2bf(v * v);
      }
    }
  }
}

// ---------------- legacy PV (fallback tiers): m97 core ----------------
__global__ __launch_bounds__(256) void gpv_kernel(
    const short* __restrict__ P, const short* __restrict__ vT,
    const short* __restrict__ u, short* __restrict__ g,
    long sp, long sv, long su)
{
  __shared__ __align__(16) short sm[8192];
  int tid = threadIdx.x;
  const short* Pz = P + (size_t)blockIdx.z * sp;
  const short* vz = vT + (size_t)blockIdx.z * sv;
  const short* uz = u + (size_t)blockIdx.z * su;
  short* gz = g + (size_t)blockIdx.z * su;
  size_t m0 = (size_t)blockIdx.x * 128, n0 = (size_t)blockIdx.y * 128;
  f32x4 acc[4][4];
  gemm_core(Pz, vz, LLL, LLL, LLL, m0, n0, tid, sm, acc);
  int wid = tid >> 6, lane = tid & 63;
  int wr = (wid >> 1) * 64, wc = (wid & 1) * 64;
  int lr = lane & 15;
  #pragma unroll
  for (int m = 0; m < 4; m++) {
    #pragma unroll
    for (int n = 0; n < 4; n++) {
      int col = (int)n0 + wc + n * 16 + lr;
      int rowb = (int)m0 + wr + m * 16 + (lane >> 4) * 4;
      #pragma unroll
      for (int r = 0; r < 4; r++) {
        size_t idx = (size_t)(rowb + r) * EE + col;
        gz[idx] = f2bf(bf2f(uz[idx]) * acc[m][n][r]);
      }
    }
  }
}

// ---------------- PV, 256x256 8-phase pipeline (T2+T3+T4+T5) ----------------
// LDS half-tile [128][64] shorts; swizzle (G4 recipe): short-col ^= (row&7)<<3
// (16-B granule over 3 row bits -> 8-slot spread, residual 2-way = free).
// Applied on pre-swizzled global source (write side) and on ds_read (read side).
__global__ __launch_bounds__(512, 2) void gpv8_kernel(
    const short* __restrict__ Pg, const short* __restrict__ vTg,
    const short* __restrict__ ug, short* __restrict__ gg)
{
  extern __shared__ __align__(16) short sm[];
  const int b = blockIdx.z;
  const size_t m0 = (size_t)blockIdx.x * 256;
  const size_t n0 = (size_t)blockIdx.y * 256;
  const short* A  = Pg  + (size_t)b * LLL * LLL;     // [4096][4096]
  const short* Bv = vTg + (size_t)b * EE * LLL;      // [1024][4096]
  const int tid = threadIdx.x, w = tid >> 6, l = tid & 63;
  const int lr = l & 15;
  // staging source pre-swizzle: lane l writes LDS row (l>>3), col-slot (l&7)*8
  const int colsrc = ((l & 7) * 8) ^ ((l >> 3) << 3);
  const short* srcA = A  + (m0 + w * 8 + (l >> 3)) * LLL + colsrc;
  const short* srcB = Bv + (n0 + w * 8 + (l >> 3)) * LLL + colsrc;
  // ds_read swizzled k-columns: row&7 == l&7 for all fragment rows
  const int csw0 = ((l >> 4) * 8) ^ ((l & 7) << 3);
  const int csw1 = (32 + (l >> 4) * 8) ^ ((l & 7) << 3);
  const int AhalfOff = (w >> 2) * 8192 + lr * 64;
  const int BhalfOff = 16384 + ((w & 3) >> 1) * 8192 + ((w & 1) * 64 + lr) * 64;

  #define STA8(bf_, h_, q_, kt_) gld16(srcA + ((h_) * 128 + (q_) * 64) * (size_t)LLL + (kt_) * 64, \
                                       &sm[(bf_) * 32768 + (h_) * 8192 + (q_) * 4096 + w * 512])
  #define STB8(bf_, h_, q_, kt_) gld16(srcB + ((h_) * 128 + (q_) * 64) * (size_t)LLL + (kt_) * 64, \
                                       &sm[(bf_) * 32768 + 16384 + (h_) * 8192 + (q_) * 4096 + w * 512])

  f32x4 acc[8][4];
  #pragma unroll
  for (int m = 0; m < 8; m++)
    #pragma unroll
    for (int n = 0; n < 4; n++) acc[m][n] = (f32x4){0.f, 0.f, 0.f, 0.f};
  short8 Af[4][2], Bf0[2][2], Bf1[2][2];

  // prologue: tile0 fully (8 units), tile1 A-lows (2 units)
  STA8(0, 0, 0, 0); STA8(0, 1, 0, 0); STA8(0, 0, 1, 0); STA8(0, 1, 1, 0);
  STB8(0, 0, 0, 0); STB8(0, 0, 1, 0); STB8(0, 1, 0, 0); STB8(0, 1, 1, 0);
  STA8(1, 0, 0, 1); STA8(1, 1, 0, 1);
  asm volatile("s_waitcnt vmcnt(2)" ::: "memory");
  SBAR();
  __builtin_amdgcn_sched_barrier(0);

  const int T = LLL / 64;   // 64 K-tiles
  for (int t = 0; t < T; ++t) {
    const int buf = t & 1, nb = buf ^ 1;
    short* Ab = sm + buf * 32768 + AhalfOff;
    short* Bb = sm + buf * 32768 + BhalfOff;
    // ---- q1: quadrant (mh0, nh0)
    if (t + 1 < T) STA8(nb, 0, 1, t + 1);
    #pragma unroll
    for (int i = 0; i < 4; ++i) {
      Af[i][0] = *(const short8*)&Ab[i * 1024 + csw0];
      Af[i][1] = *(const short8*)&Ab[i * 1024 + csw1];
    }
    #pragma unroll
    for (int j = 0; j < 2; ++j) {
      Bf0[j][0] = *(const short8*)&Bb[j * 1024 + csw0];
      Bf0[j][1] = *(const short8*)&Bb[j * 1024 + csw1];
    }
    SBAR();
    __builtin_amdgcn_s_setprio(1);
    #pragma unroll
    for (int i = 0; i < 4; ++i)
      #pragma unroll
      for (int j = 0; j < 2; ++j) {
        MFMA16(Af[i][0], Bf0[j][0], acc[i][j]);
        MFMA16(Af[i][1], Bf0[j][1], acc[i][j]);
      }
    __builtin_amdgcn_s_setprio(0);
    SBAR();
    // ---- q2: quadrant (mh0, nh1)
    if (t + 1 < T) STA8(nb, 1, 1, t + 1);
    #pragma unroll
    for (int j = 0; j < 2; ++j) {
      Bf1[j][0] = *(const short8*)&Bb[2048 + j * 1024 + csw0];
      Bf1[j][1] = *(const short8*)&Bb[2048 + j * 1024 + csw1];
    }
    SBAR();
    __builtin_amdgcn_s_setprio(1);
    #pragma unroll
    for (int i = 0; i < 4; ++i)
      #pragma unroll
      for (int j = 0; j < 2; ++j) {
        MFMA16(Af[i][0], Bf1[j][0], acc[i][2 + j]);
        MFMA16(Af[i][1], Bf1[j][1], acc[i][2 + j]);
      }
    __builtin_amdgcn_s_setprio(0);
    SBAR();
    // ---- q3: quadrant (mh1, nh1)
    if (t + 1 < T) { STB8(nb, 0, 0, t + 1); STB8(nb, 0, 1, t + 1); }
    #pragma unroll
    for (int i = 0; i < 4; ++i) {
      Af[i][0] = *(const short8*)&Ab[4096 + i * 1024 + csw0];
      Af[i][1] = *(const short8*)&Ab[4096 + i * 1024 + csw1];
    }
    SBAR();
    __builtin_amdgcn_s_setprio(1);
    #pragma unroll
    for (int i = 0; i < 4; ++i)
      #pragma unroll
      for (int j = 0; j < 2; ++j) {
        MFMA16(Af[i][0], Bf1[j][0], acc[4 + i][2 + j]);
        MFMA16(Af[i][1], Bf1[j][1], acc[4 + i][2 + j]);
      }
    __builtin_amdgcn_s_setprio(0);
    SBAR();
    // ---- q4: quadrant (mh1, nh0) + tile boundary
    if (t + 1 < T) { STB8(nb, 1, 0, t + 1); STB8(nb, 1, 1, t + 1); }
    if (t + 2 < T) { STA8(buf, 0, 0, t + 2); STA8(buf, 1, 0, t + 2); }
    SBAR();
    __builtin_amdgcn_s_setprio(1);
    #pragma unroll
    for (int i = 0; i < 4; ++i)
      #pragma unroll
      for (int j = 0; j < 2; ++j) {
        MFMA16(Af[i][0], Bf0[j][0], acc[4 + i][j]);
        MFMA16(Af[i][1], Bf0[j][1], acc[4 + i][j]);
      }
    __builtin_amdgcn_s_setprio(0);
    if (t < T - 2) {
      asm volatile("s_waitcnt vmcnt(2)" ::: "memory");
      SBAR();
      __builtin_amdgcn_sched_barrier(0);
    } else if (t == T - 2) {
      asm volatile("s_waitcnt vmcnt(0)" ::: "memory");
      SBAR();
      __builtin_amdgcn_sched_barrier(0);
    }
  }
  // epilogue: g = u * acc
  const short* ub_ = ug + (size_t)b * LLL * EE;
  short* gb_ = gg + (size_t)b * LLL * EE;
  const int rowb0 = (int)m0 + (w >> 2) * 128 + (l >> 4) * 4;
  const int colb0 = (int)n0 + (w & 3) * 64 + lr;
  #pragma unroll
  for (int mf = 0; mf < 8; ++mf) {
    #pragma unroll
    for (int nf = 0; nf < 4; ++nf) {
      int col = colb0 + nf * 16;
      #pragma unroll
      for (int r = 0; r < 4; ++r) {
        size_t idx = (size_t)(rowb0 + mf * 16 + r) * EE + col;
        gb_[idx] = f2bf(bf2f(ub_[idx]) * acc[mf][nf][r]);
      }
    }
  }
  #undef STA8
  #undef STB8
}

// ---------------- GEMM2: g x W_outT + bias + residual (fp32 out) ----------------
__global__ __launch_bounds__(256) void gout_kernel(
    const short* __restrict__ A, const short* __restrict__ Bw,
    const float* __restrict__ b_out, const float* __restrict__ x,
    float* __restrict__ out)
{
  __shared__ __align__(16) short sm[8192];
  int tid = threadIdx.x;
  size_t m0 = (size_t)blockIdx.x * 128, n0 = (size_t)blockIdx.y * 128;
  f32x4 acc[4][4];
  gemm_core(A, Bw, EE, EE, EE, m0, n0, tid, sm, acc);
  int wid = tid >> 6, lane = tid & 63;
  int wr = (wid >> 1) * 64, wc = (wid & 1) * 64;
  int lr = lane & 15;
  #pragma unroll
  for (int m = 0; m < 4; m++) {
    #pragma unroll
    for (int n = 0; n < 4; n++) {
      int col = (int)n0 + wc + n * 16 + lr;
      float bias = b_out[col];
      int rowb = (int)m0 + wr + m * 16 + (lane >> 4) * 4;
      #pragma unroll
      for (int r = 0; r < 4; r++) {
        size_t idx = (size_t)(rowb + r) * DIMD + col;
        out[idx] = acc[m][n][r] + bias + x[idx];
      }
    }
  }
}

extern "C" void kernel_launch(void* const* d_in, const int* in_sizes, int n_in,
                              void* d_out, int out_size, void* d_ws, size_t ws_size,
                              hipStream_t stream) {
  const float* x     = (const float*)d_in[0];
  const float* W_uv  = (const float*)d_in[1];
  const float* b_uv  = (const float*)d_in[2];
  const float* gamma = (const float*)d_in[3];
  const float* beta  = (const float*)d_in[4];
  const float* W_out = (const float*)d_in[5];
  const float* b_out = (const float*)d_in[6];
  const float* ln_w  = (const float*)d_in[7];
  const float* ln_b  = (const float*)d_in[8];
  float* out = (float*)d_out;

  char* ws = (char*)d_ws;
  short* W_uvT  = (short*)(ws);
  short* W_outT = (short*)(ws + 2228224);
  short* xn     = (short*)(ws + 3276800);
  short* qb     = (short*)(ws + 20054016);
  short* kb     = (short*)(ws + 24248320);
  short* ub     = (short*)(ws + 28442624);
  short* vTb    = (short*)(ws + 61997056);
  short* gb     = (short*)(ws + 95551488);
  short* Pb     = (short*)(ws + 129105920);

  prep_kernel<<<dim3((NUV * DIMD + 255) / 256), 256, 0, stream>>>(W_uv, W_out, W_uvT, W_outT);
  ln_kernel<<<dim3(NROW), 256, 0, stream>>>(x, ln_w, ln_b, xn);
  guv_kernel<<<dim3(NROW / 128, NUV / 128), 256, 0, stream>>>(xn, W_uvT, b_uv, gamma, beta, ub, vTb, qb, kb);

  const long SQ = (long)LLL * SSS;
  const long SP = (long)LLL * LLL;
  const long SV = (long)EE * LLL;
  const long SU = (long)LLL * EE;

  if (ws_size >= 129105920ull + 134217728ull) {
    gqk_kernel<<<dim3(32, 32, 4), 256, 0, stream>>>(qb, kb, Pb, SQ, SQ, SP);
    gpv8_kernel<<<dim3(16, 4, 4), 512, 131072, stream>>>(Pb, vTb, ub, gb);
  } else if (ws_size >= 129105920ull + 33554432ull) {
    for (int b = 0; b < 4; b++) {
      gqk_kernel<<<dim3(32, 32, 1), 256, 0, stream>>>(qb + (size_t)b * SQ, kb + (size_t)b * SQ, Pb, 0, 0, 0);
      gpv_kernel<<<dim3(32, 8, 1), 256, 0, stream>>>(Pb, vTb + (size_t)b * SV, ub + (size_t)b * SU, gb + (size_t)b * SU, 0, 0, 0);
    }
  } else {
    short* Pc = xn;
    for (int b = 0; b < 4; b++) {
      for (int h = 0; h < 2; h++) {
        size_t rowoff = (size_t)b * LLL + (size_t)h * 2048;
        gqk_kernel<<<dim3(16, 32, 1), 256, 0, stream>>>(qb + rowoff * SSS, kb + (size_t)b * SQ, Pc, 0, 0, 0);
        gpv_kernel<<<dim3(16, 8, 1), 256, 0, stream>>>(Pc, vTb + (size_t)b * SV, ub + rowoff * EE, gb + rowoff * EE, 0, 0, 0);
      }
    }
  }

  gout_kernel<<<dim3(NROW / 128, DIMD / 128), 256, 0, stream>>>(gb, W_outT, b_out, x, out);
}

// Round 5
// 297.010 us; speedup vs baseline: 4.3588x; 1.0730x over previous
//
#include <hip/hip_runtime.h>

typedef __attribute__((ext_vector_type(8))) short short8;
typedef __attribute__((ext_vector_type(4))) float f32x4;

#define DIMD 512
#define EE 1024
#define SSS 128
#define LLL 4096
#define NROW 16384   // B*L
#define NUV 2176     // 2E+S

__device__ __forceinline__ short f2bf(float f) {
  union { float f; unsigned u; } un; un.f = f;
  unsigned r = un.u + 0x7FFFu + ((un.u >> 16) & 1u);
  return (short)(r >> 16);
}
__device__ __forceinline__ float bf2f(short s) {
  union { unsigned u; float f; } un;
  un.u = ((unsigned)(unsigned short)s) << 16;
  return un.f;
}
__device__ __forceinline__ float silu_f(float x) {
  return x / (1.0f + __expf(-x));
}

__device__ __forceinline__ void gld16(const short* g, short* l) {
  __builtin_amdgcn_global_load_lds(
      (const __attribute__((address_space(1))) unsigned int*)g,
      (__attribute__((address_space(3))) unsigned int*)l, 16, 0, 0);
}

#define MFMA16(a, b, c) c = __builtin_amdgcn_mfma_f32_16x16x32_bf16(a, b, c, 0, 0, 0)
#define SBAR() asm volatile("s_barrier" ::: "memory")
#define VMCNT(n) asm volatile("s_waitcnt vmcnt(" #n ")" ::: "memory")

// ---------------- prep: transpose+cast weights to bf16 ----------------
__global__ void prep_kernel(const float* __restrict__ W_uv, const float* __restrict__ W_out,
                            short* __restrict__ W_uvT, short* __restrict__ W_outT) {
  int i = blockIdx.x * blockDim.x + threadIdx.x;
  if (i < NUV * DIMD) {
    int c = i >> 9, d = i & (DIMD - 1);
    W_uvT[i] = f2bf(W_uv[(size_t)d * NUV + c]);
  }
  if (i < DIMD * EE) {
    int d = i >> 10, e = i & (EE - 1);
    W_outT[i] = f2bf(W_out[(size_t)e * DIMD + d]);
  }
}

// ---------------- layernorm -> xn bf16 ----------------
__global__ __launch_bounds__(256) void ln_kernel(const float* __restrict__ x,
    const float* __restrict__ w, const float* __restrict__ bb, short* __restrict__ xn) {
  int row = blockIdx.x;
  int tid = threadIdx.x;
  const float2* xr = (const float2*)(x + (size_t)row * DIMD);
  float2 v = xr[tid];
  float s = v.x + v.y, ss = v.x * v.x + v.y * v.y;
  #pragma unroll
  for (int off = 32; off >= 1; off >>= 1) {
    s += __shfl_down(s, off);
    ss += __shfl_down(ss, off);
  }
  __shared__ float ps[8];
  if ((tid & 63) == 0) { ps[tid >> 6] = s; ps[4 + (tid >> 6)] = ss; }
  __syncthreads();
  s = ps[0] + ps[1] + ps[2] + ps[3];
  ss = ps[4] + ps[5] + ps[6] + ps[7];
  float mu = s * (1.0f / DIMD);
  float var = ss * (1.0f / DIMD) - mu * mu;
  float inv = rsqrtf(var + 1e-5f);
  float2 wv = ((const float2*)w)[tid];
  float2 bv = ((const float2*)bb)[tid];
  short2 o;
  o.x = f2bf((v.x - mu) * inv * wv.x + bv.x);
  o.y = f2bf((v.y - mu) * inv * wv.y + bv.y);
  *(short2*)&xn[(size_t)row * DIMD + tid * 2] = o;
}

// ---------------- m97-style GEMM core: 128x128 tile, 4 waves, BK=32 ----------------
__device__ __forceinline__ void gemm_core(const short* __restrict__ A, const short* __restrict__ B,
                                          int lda, int ldb, int K, size_t m0, size_t n0,
                                          int tid, short* sm, f32x4 acc[4][4]) {
  short* As = sm;
  short* Bs = sm + 4096;
  int wid = tid >> 6, lane = tid & 63;
  int wr = (wid >> 1) * 64, wc = (wid & 1) * 64;
  int lr = lane & 15, lk = (lane >> 4) * 8;
  int r0 = tid >> 2, c0 = (tid & 3) * 8;
  #pragma unroll
  for (int m = 0; m < 4; m++)
    #pragma unroll
    for (int n = 0; n < 4; n++) acc[m][n] = (f32x4){0.f, 0.f, 0.f, 0.f};
  for (int k0 = 0; k0 < K; k0 += 32) {
    gld16(&A[(m0 + r0) * lda + k0 + c0],      &As[wid * 512]);
    gld16(&A[(m0 + 64 + r0) * lda + k0 + c0], &As[2048 + wid * 512]);
    gld16(&B[(n0 + r0) * ldb + k0 + c0],      &Bs[wid * 512]);
    gld16(&B[(n0 + 64 + r0) * ldb + k0 + c0], &Bs[2048 + wid * 512]);
    __syncthreads();
    short8 af[4], bf[4];
    #pragma unroll
    for (int m = 0; m < 4; m++) af[m] = *(short8*)&As[(wr + m * 16 + lr) * 32 + lk];
    #pragma unroll
    for (int n = 0; n < 4; n++) bf[n] = *(short8*)&Bs[(wc + n * 16 + lr) * 32 + lk];
    #pragma unroll
    for (int m = 0; m < 4; m++)
      #pragma unroll
      for (int n = 0; n < 4; n++)
        MFMA16(af[m], bf[n], acc[m][n]);
    __syncthreads();
  }
}

// ---------------- GEMM1: xn x W_uvT + fused silu/affine epilogue ----------------
__global__ __launch_bounds__(256) void guv_kernel(
    const short* __restrict__ A, const short* __restrict__ Bw,
    const float* __restrict__ b_uv, const float* __restrict__ gamma, const float* __restrict__ beta,
    short* __restrict__ u_out, short* __restrict__ vT_out,
    short* __restrict__ q_out, short* __restrict__ k_out)
{
  __shared__ __align__(16) short sm[8192];
  int tid = threadIdx.x;
  size_t m0 = (size_t)blockIdx.x * 128, n0 = (size_t)blockIdx.y * 128;
  f32x4 acc[4][4];
  gemm_core(A, Bw, DIMD, DIMD, DIMD, m0, n0, tid, sm, acc);
  int wid = tid >> 6, lane = tid & 63;
  int wr = (wid >> 1) * 64, wc = (wid & 1) * 64;
  int lr = lane & 15;
  #pragma unroll
  for (int m = 0; m < 4; m++) {
    #pragma unroll
    for (int n = 0; n < 4; n++) {
      int col = (int)n0 + wc + n * 16 + lr;
      float bias = b_uv[col];
      int rowb = (int)m0 + wr + m * 16 + (lane >> 4) * 4;
      if (n0 < 1024) {
        #pragma unroll
        for (int r = 0; r < 4; r++)
          u_out[(size_t)(rowb + r) * EE + col] = f2bf(silu_f(acc[m][n][r] + bias));
      } else if (n0 < 2048) {
        int e = col - 1024, bb = rowb >> 12, lb = rowb & (LLL - 1);
        short4 o;
        o.x = f2bf(silu_f(acc[m][n][0] + bias));
        o.y = f2bf(silu_f(acc[m][n][1] + bias));
        o.z = f2bf(silu_f(acc[m][n][2] + bias));
        o.w = f2bf(silu_f(acc[m][n][3] + bias));
        *(short4*)&vT_out[((size_t)bb * EE + e) * LLL + lb] = o;
      } else {
        int s = col - 2048;
        float g0 = gamma[s], g1 = gamma[SSS + s], be0 = beta[s], be1 = beta[SSS + s];
        #pragma unroll
        for (int r = 0; r < 4; r++) {
          float val = acc[m][n][r] + bias;
          q_out[(size_t)(rowb + r) * SSS + s] = f2bf(val * g0 + be0);
          k_out[(size_t)(rowb + r) * SSS + s] = f2bf(val * g1 + be1);
        }
      }
    }
  }
}

// ---------------- QK^T -> P = relu(qk/sqrt(S))^2 (bf16) ----------------
__global__ __launch_bounds__(256) void gqk_kernel(
    const short* __restrict__ q, const short* __restrict__ k, short* __restrict__ P,
    long sq, long sk, long sp)
{
  __shared__ __align__(16) short sm[8192];
  int tid = threadIdx.x;
  const short* qz = q + (size_t)blockIdx.z * sq;
  const short* kz = k + (size_t)blockIdx.z * sk;
  short* Pz = P + (size_t)blockIdx.z * sp;
  size_t m0 = (size_t)blockIdx.x * 128, n0 = (size_t)blockIdx.y * 128;
  f32x4 acc[4][4];
  gemm_core(qz, kz, SSS, SSS, SSS, m0, n0, tid, sm, acc);
  int wid = tid >> 6, lane = tid & 63;
  int wr = (wid >> 1) * 64, wc = (wid & 1) * 64;
  int lr = lane & 15;
  const float scale = 0.08838834764831845f;
  #pragma unroll
  for (int m = 0; m < 4; m++) {
    #pragma unroll
    for (int n = 0; n < 4; n++) {
      int col = (int)n0 + wc + n * 16 + lr;
      int rowb = (int)m0 + wr + m * 16 + (lane >> 4) * 4;
      #pragma unroll
      for (int r = 0; r < 4; r++) {
        float v = fmaxf(acc[m][n][r] * scale, 0.f);
        Pz[(size_t)(rowb + r) * LLL + col] = f2bf(v * v);
      }
    }
  }
}

// ---------------- legacy PV (fallback tiers): m97 core ----------------
__global__ __launch_bounds__(256) void gpv_kernel(
    const short* __restrict__ P, const short* __restrict__ vT,
    const short* __restrict__ u, short* __restrict__ g,
    long sp, long sv, long su)
{
  __shared__ __align__(16) short sm[8192];
  int tid = threadIdx.x;
  const short* Pz = P + (size_t)blockIdx.z * sp;
  const short* vz = vT + (size_t)blockIdx.z * sv;
  const short* uz = u + (size_t)blockIdx.z * su;
  short* gz = g + (size_t)blockIdx.z * su;
  size_t m0 = (size_t)blockIdx.x * 128, n0 = (size_t)blockIdx.y * 128;
  f32x4 acc[4][4];
  gemm_core(Pz, vz, LLL, LLL, LLL, m0, n0, tid, sm, acc);
  int wid = tid >> 6, lane = tid & 63;
  int wr = (wid >> 1) * 64, wc = (wid & 1) * 64;
  int lr = lane & 15;
  #pragma unroll
  for (int m = 0; m < 4; m++) {
    #pragma unroll
    for (int n = 0; n < 4; n++) {
      int col = (int)n0 + wc + n * 16 + lr;
      int rowb = (int)m0 + wr + m * 16 + (lane >> 4) * 4;
      #pragma unroll
      for (int r = 0; r < 4; r++) {
        size_t idx = (size_t)(rowb + r) * EE + col;
        gz[idx] = f2bf(bf2f(uz[idx]) * acc[m][n][r]);
      }
    }
  }
}

// ---------------- PV, 256x256 8-phase pipeline (T2+T3+T4+T5) ----------------
// Uniform stage schedule: 2 loads/phase, vmcnt(6) at every phase end
// (load issued at phase p completes by end of p+3, read at p+4).
// q1: stage B-lows(t+1)   [region dead since t-1 q1]
// q2: stage B-highs(t+1)  [dead since t-1 q2]
// q3: stage A-highs(t+1)  [dead since t-1 q3]
// q4: stage A-lows(t+2) into cur buf [dead since t q1]
__global__ __launch_bounds__(512, 2) void gpv8_kernel(
    const short* __restrict__ Pg, const short* __restrict__ vTg,
    const short* __restrict__ ug, short* __restrict__ gg)
{
  extern __shared__ __align__(16) short sm[];
  const int b = blockIdx.z;
  const size_t m0 = (size_t)blockIdx.x * 256;
  const size_t n0 = (size_t)blockIdx.y * 256;
  const short* A  = Pg  + (size_t)b * LLL * LLL;     // [4096][4096]
  const short* Bv = vTg + (size_t)b * EE * LLL;      // [1024][4096]
  const int tid = threadIdx.x, w = tid >> 6, l = tid & 63;
  const int lr = l & 15;
  // staging source pre-swizzle: lane l writes LDS row (l>>3), col-slot (l&7)*8
  const int colsrc = ((l & 7) * 8) ^ ((l >> 3) << 3);
  const short* srcA = A  + (m0 + w * 8 + (l >> 3)) * LLL + colsrc;
  const short* srcB = Bv + (n0 + w * 8 + (l >> 3)) * LLL + colsrc;
  // ds_read swizzled k-columns: row&7 == l&7 for all fragment rows
  const int csw0 = ((l >> 4) * 8) ^ ((l & 7) << 3);
  const int csw1 = (32 + (l >> 4) * 8) ^ ((l & 7) << 3);
  const int AhalfOff = (w >> 2) * 8192 + lr * 64;
  const int BhalfOff = 16384 + ((w & 3) >> 1) * 8192 + ((w & 1) * 64 + lr) * 64;

  #define STA8(bf_, h_, q_, kt_) gld16(srcA + ((h_) * 128 + (q_) * 64) * (size_t)LLL + (kt_) * 64, \
                                       &sm[(bf_) * 32768 + (h_) * 8192 + (q_) * 4096 + w * 512])
  #define STB8(bf_, h_, q_, kt_) gld16(srcB + ((h_) * 128 + (q_) * 64) * (size_t)LLL + (kt_) * 64, \
                                       &sm[(bf_) * 32768 + 16384 + (h_) * 8192 + (q_) * 4096 + w * 512])

  f32x4 acc[8][4];
  #pragma unroll
  for (int m = 0; m < 8; m++)
    #pragma unroll
    for (int n = 0; n < 4; n++) acc[m][n] = (f32x4){0.f, 0.f, 0.f, 0.f};
  short8 Af[4][2], Bf0[2][2], Bf1[2][2];

  // prologue: tile0 all 8 units, then tile1 A-lows (kept in flight)
  STA8(0, 0, 0, 0); STA8(0, 1, 0, 0);   // A-lows t0
  STB8(0, 0, 0, 0); STB8(0, 1, 0, 0);   // B-lows t0
  STB8(0, 0, 1, 0); STB8(0, 1, 1, 0);   // B-highs t0
  STA8(0, 0, 1, 0); STA8(0, 1, 1, 0);   // A-highs t0
  STA8(1, 0, 0, 1); STA8(1, 1, 0, 1);   // A-lows t1
  VMCNT(2);
  SBAR();
  __builtin_amdgcn_sched_barrier(0);

  const int T = LLL / 64;   // 64 K-tiles
  for (int t = 0; t < T; ++t) {
    const int buf = t & 1, nb = buf ^ 1;
    short* Ab = sm + buf * 32768 + AhalfOff;
    short* Bb = sm + buf * 32768 + BhalfOff;
    // ---- q1: quadrant (mh0, nh0); reads A-lows + B-lows
    if (t + 1 < T) { STB8(nb, 0, 0, t + 1); STB8(nb, 1, 0, t + 1); }
    #pragma unroll
    for (int i = 0; i < 4; ++i) {
      Af[i][0] = *(const short8*)&Ab[i * 1024 + csw0];
      Af[i][1] = *(const short8*)&Ab[i * 1024 + csw1];
    }
    #pragma unroll
    for (int j = 0; j < 2; ++j) {
      Bf0[j][0] = *(const short8*)&Bb[j * 1024 + csw0];
      Bf0[j][1] = *(const short8*)&Bb[j * 1024 + csw1];
    }
    SBAR();
    __builtin_amdgcn_s_setprio(1);
    #pragma unroll
    for (int i = 0; i < 4; ++i)
      #pragma unroll
      for (int j = 0; j < 2; ++j) {
        MFMA16(Af[i][0], Bf0[j][0], acc[i][j]);
        MFMA16(Af[i][1], Bf0[j][1], acc[i][j]);
      }
    __builtin_amdgcn_s_setprio(0);
    if (t < T - 1) { VMCNT(6); } else { VMCNT(2); }
    SBAR();
    // ---- q2: quadrant (mh0, nh1); reads B-highs
    if (t + 1 < T) { STB8(nb, 0, 1, t + 1); STB8(nb, 1, 1, t + 1); }
    #pragma unroll
    for (int j = 0; j < 2; ++j) {
      Bf1[j][0] = *(const short8*)&Bb[2048 + j * 1024 + csw0];
      Bf1[j][1] = *(const short8*)&Bb[2048 + j * 1024 + csw1];
    }
    SBAR();
    __builtin_amdgcn_s_setprio(1);
    #pragma unroll
    for (int i = 0; i < 4; ++i)
      #pragma unroll
      for (int j = 0; j < 2; ++j) {
        MFMA16(Af[i][0], Bf1[j][0], acc[i][2 + j]);
        MFMA16(Af[i][1], Bf1[j][1], acc[i][2 + j]);
      }
    __builtin_amdgcn_s_setprio(0);
    if (t < T - 1) { VMCNT(6); } else { VMCNT(0); }
    SBAR();
    // ---- q3: quadrant (mh1, nh1); reads A-highs
    if (t + 1 < T) { STA8(nb, 0, 1, t + 1); STA8(nb, 1, 1, t + 1); }
    #pragma unroll
    for (int i = 0; i < 4; ++i) {
      Af[i][0] = *(const short8*)&Ab[4096 + i * 1024 + csw0];
      Af[i][1] = *(const short8*)&Ab[4096 + i * 1024 + csw1];
    }
    SBAR();
    __builtin_amdgcn_s_setprio(1);
    #pragma unroll
    for (int i = 0; i < 4; ++i)
      #pragma unroll
      for (int j = 0; j < 2; ++j) {
        MFMA16(Af[i][0], Bf1[j][0], acc[4 + i][2 + j]);
        MFMA16(Af[i][1], Bf1[j][1], acc[4 + i][2 + j]);
      }
    __builtin_amdgcn_s_setprio(0);
    if (t < T - 1) { VMCNT(6); } else { VMCNT(0); }
    SBAR();
    // ---- q4: quadrant (mh1, nh0); no LDS reads (Af/Bf0 live in regs)
    if (t + 2 < T) { STA8(buf, 0, 0, t + 2); STA8(buf, 1, 0, t + 2); }
    __builtin_amdgcn_s_setprio(1);
    #pragma unroll
    for (int i = 0; i < 4; ++i)
      #pragma unroll
      for (int j = 0; j < 2; ++j) {
        MFMA16(Af[i][0], Bf0[j][0], acc[4 + i][j]);
        MFMA16(Af[i][1], Bf0[j][1], acc[4 + i][j]);
      }
    __builtin_amdgcn_s_setprio(0);
    if (t < T - 2) { VMCNT(6); } else if (t == T - 2) { VMCNT(4); } else { VMCNT(0); }
    SBAR();
    __builtin_amdgcn_sched_barrier(0);
  }
  // epilogue: g = u * acc
  const short* ub_ = ug + (size_t)b * LLL * EE;
  short* gb_ = gg + (size_t)b * LLL * EE;
  const int rowb0 = (int)m0 + (w >> 2) * 128 + (l >> 4) * 4;
  const int colb0 = (int)n0 + (w & 3) * 64 + lr;
  #pragma unroll
  for (int mf = 0; mf < 8; ++mf) {
    #pragma unroll
    for (int nf = 0; nf < 4; ++nf) {
      int col = colb0 + nf * 16;
      #pragma unroll
      for (int r = 0; r < 4; ++r) {
        size_t idx = (size_t)(rowb0 + mf * 16 + r) * EE + col;
        gb_[idx] = f2bf(bf2f(ub_[idx]) * acc[mf][nf][r]);
      }
    }
  }
  #undef STA8
  #undef STB8
}

// ---------------- GEMM2: g x W_outT + bias + residual (fp32 out) ----------------
__global__ __launch_bounds__(256) void gout_kernel(
    const short* __restrict__ A, const short* __restrict__ Bw,
    const float* __restrict__ b_out, const float* __restrict__ x,
    float* __restrict__ out)
{
  __shared__ __align__(16) short sm[8192];
  int tid = threadIdx.x;
  size_t m0 = (size_t)blockIdx.x * 128, n0 = (size_t)blockIdx.y * 128;
  f32x4 acc[4][4];
  gemm_core(A, Bw, EE, EE, EE, m0, n0, tid, sm, acc);
  int wid = tid >> 6, lane = tid & 63;
  int wr = (wid >> 1) * 64, wc = (wid & 1) * 64;
  int lr = lane & 15;
  #pragma unroll
  for (int m = 0; m < 4; m++) {
    #pragma unroll
    for (int n = 0; n < 4; n++) {
      int col = (int)n0 + wc + n * 16 + lr;
      float bias = b_out[col];
      int rowb = (int)m0 + wr + m * 16 + (lane >> 4) * 4;
      #pragma unroll
      for (int r = 0; r < 4; r++) {
        size_t idx = (size_t)(rowb + r) * DIMD + col;
        out[idx] = acc[m][n][r] + bias + x[idx];
      }
    }
  }
}

extern "C" void kernel_launch(void* const* d_in, const int* in_sizes, int n_in,
                              void* d_out, int out_size, void* d_ws, size_t ws_size,
                              hipStream_t stream) {
  const float* x     = (const float*)d_in[0];
  const float* W_uv  = (const float*)d_in[1];
  const float* b_uv  = (const float*)d_in[2];
  const float* gamma = (const float*)d_in[3];
  const float* beta  = (const float*)d_in[4];
  const float* W_out = (const float*)d_in[5];
  const float* b_out = (const float*)d_in[6];
  const float* ln_w  = (const float*)d_in[7];
  const float* ln_b  = (const float*)d_in[8];
  float* out = (float*)d_out;

  char* ws = (char*)d_ws;
  short* W_uvT  = (short*)(ws);
  short* W_outT = (short*)(ws + 2228224);
  short* xn     = (short*)(ws + 3276800);
  short* qb     = (short*)(ws + 20054016);
  short* kb     = (short*)(ws + 24248320);
  short* ub     = (short*)(ws + 28442624);
  short* vTb    = (short*)(ws + 61997056);
  short* gb     = (short*)(ws + 95551488);
  short* Pb     = (short*)(ws + 129105920);

  prep_kernel<<<dim3((NUV * DIMD + 255) / 256), 256, 0, stream>>>(W_uv, W_out, W_uvT, W_outT);
  ln_kernel<<<dim3(NROW), 256, 0, stream>>>(x, ln_w, ln_b, xn);
  guv_kernel<<<dim3(NROW / 128, NUV / 128), 256, 0, stream>>>(xn, W_uvT, b_uv, gamma, beta, ub, vTb, qb, kb);

  const long SQ = (long)LLL * SSS;
  const long SP = (long)LLL * LLL;
  const long SV = (long)EE * LLL;
  const long SU = (long)LLL * EE;

  if (ws_size >= 129105920ull + 134217728ull) {
    gqk_kernel<<<dim3(32, 32, 4), 256, 0, stream>>>(qb, kb, Pb, SQ, SQ, SP);
    gpv8_kernel<<<dim3(16, 4, 4), 512, 131072, stream>>>(Pb, vTb, ub, gb);
  } else if (ws_size >= 129105920ull + 33554432ull) {
    for (int b = 0; b < 4; b++) {
      gqk_kernel<<<dim3(32, 32, 1), 256, 0, stream>>>(qb + (size_t)b * SQ, kb + (size_t)b * SQ, Pb, 0, 0, 0);
      gpv_kernel<<<dim3(32, 8, 1), 256, 0, stream>>>(Pb, vTb + (size_t)b * SV, ub + (size_t)b * SU, gb + (size_t)b * SU, 0, 0, 0);
    }
  } else {
    short* Pc = xn;
    for (int b = 0; b < 4; b++) {
      for (int h = 0; h < 2; h++) {
        size_t rowoff = (size_t)b * LLL + (size_t)h * 2048;
        gqk_kernel<<<dim3(16, 32, 1), 256, 0, stream>>>(qb + rowoff * SSS, kb + (size_t)b * SQ, Pc, 0, 0, 0);
        gpv_kernel<<<dim3(16, 8, 1), 256, 0, stream>>>(Pc, vTb + (size_t)b * SV, ub + rowoff * EE, gb + rowoff * EE, 0, 0, 0);
      }
    }
  }

  gout_kernel<<<dim3(NROW / 128, DIMD / 128), 256, 0, stream>>>(gb, W_outT, b_out, x, out);
}

// Round 6
// 289.721 us; speedup vs baseline: 4.4684x; 1.0252x over previous
//
#include <hip/hip_runtime.h>

typedef __attribute__((ext_vector_type(8))) short short8;
typedef __attribute__((ext_vector_type(4))) float f32x4;

#define DIMD 512
#define EE 1024
#define SSS 128
#define LLL 4096
#define NROW 16384   // B*L
#define NUV 2176     // 2E+S

__device__ __forceinline__ short f2bf(float f) {
  union { float f; unsigned u; } un; un.f = f;
  unsigned r = un.u + 0x7FFFu + ((un.u >> 16) & 1u);
  return (short)(r >> 16);
}
__device__ __forceinline__ float bf2f(short s) {
  union { unsigned u; float f; } un;
  un.u = ((unsigned)(unsigned short)s) << 16;
  return un.f;
}
__device__ __forceinline__ float silu_f(float x) {
  return x / (1.0f + __expf(-x));
}

__device__ __forceinline__ void gld16(const short* g, short* l) {
  __builtin_amdgcn_global_load_lds(
      (const __attribute__((address_space(1))) unsigned int*)g,
      (__attribute__((address_space(3))) unsigned int*)l, 16, 0, 0);
}

#define MFMA16(a, b, c) c = __builtin_amdgcn_mfma_f32_16x16x32_bf16(a, b, c, 0, 0, 0)
#define SBAR() asm volatile("s_barrier" ::: "memory")
#define VMCNT(n) asm volatile("s_waitcnt vmcnt(" #n ")" ::: "memory")

// ---------------- prep: transpose+cast weights to bf16 ----------------
__global__ void prep_kernel(const float* __restrict__ W_uv, const float* __restrict__ W_out,
                            short* __restrict__ W_uvT, short* __restrict__ W_outT) {
  int i = blockIdx.x * blockDim.x + threadIdx.x;
  if (i < NUV * DIMD) {
    int c = i >> 9, d = i & (DIMD - 1);
    W_uvT[i] = f2bf(W_uv[(size_t)d * NUV + c]);
  }
  if (i < DIMD * EE) {
    int d = i >> 10, e = i & (EE - 1);
    W_outT[i] = f2bf(W_out[(size_t)e * DIMD + d]);
  }
}

// ---------------- layernorm -> xn bf16 ----------------
__global__ __launch_bounds__(256) void ln_kernel(const float* __restrict__ x,
    const float* __restrict__ w, const float* __restrict__ bb, short* __restrict__ xn) {
  int row = blockIdx.x;
  int tid = threadIdx.x;
  const float2* xr = (const float2*)(x + (size_t)row * DIMD);
  float2 v = xr[tid];
  float s = v.x + v.y, ss = v.x * v.x + v.y * v.y;
  #pragma unroll
  for (int off = 32; off >= 1; off >>= 1) {
    s += __shfl_down(s, off);
    ss += __shfl_down(ss, off);
  }
  __shared__ float ps[8];
  if ((tid & 63) == 0) { ps[tid >> 6] = s; ps[4 + (tid >> 6)] = ss; }
  __syncthreads();
  s = ps[0] + ps[1] + ps[2] + ps[3];
  ss = ps[4] + ps[5] + ps[6] + ps[7];
  float mu = s * (1.0f / DIMD);
  float var = ss * (1.0f / DIMD) - mu * mu;
  float inv = rsqrtf(var + 1e-5f);
  float2 wv = ((const float2*)w)[tid];
  float2 bv = ((const float2*)bb)[tid];
  short2 o;
  o.x = f2bf((v.x - mu) * inv * wv.x + bv.x);
  o.y = f2bf((v.y - mu) * inv * wv.y + bv.y);
  *(short2*)&xn[(size_t)row * DIMD + tid * 2] = o;
}

// ---------------- m97-style GEMM core: 128x128 tile, 4 waves, BK=32 ----------------
__device__ __forceinline__ void gemm_core(const short* __restrict__ A, const short* __restrict__ B,
                                          int lda, int ldb, int K, size_t m0, size_t n0,
                                          int tid, short* sm, f32x4 acc[4][4]) {
  short* As = sm;
  short* Bs = sm + 4096;
  int wid = tid >> 6, lane = tid & 63;
  int wr = (wid >> 1) * 64, wc = (wid & 1) * 64;
  int lr = lane & 15, lk = (lane >> 4) * 8;
  int r0 = tid >> 2, c0 = (tid & 3) * 8;
  #pragma unroll
  for (int m = 0; m < 4; m++)
    #pragma unroll
    for (int n = 0; n < 4; n++) acc[m][n] = (f32x4){0.f, 0.f, 0.f, 0.f};
  for (int k0 = 0; k0 < K; k0 += 32) {
    gld16(&A[(m0 + r0) * lda + k0 + c0],      &As[wid * 512]);
    gld16(&A[(m0 + 64 + r0) * lda + k0 + c0], &As[2048 + wid * 512]);
    gld16(&B[(n0 + r0) * ldb + k0 + c0],      &Bs[wid * 512]);
    gld16(&B[(n0 + 64 + r0) * ldb + k0 + c0], &Bs[2048 + wid * 512]);
    __syncthreads();
    short8 af[4], bf[4];
    #pragma unroll
    for (int m = 0; m < 4; m++) af[m] = *(short8*)&As[(wr + m * 16 + lr) * 32 + lk];
    #pragma unroll
    for (int n = 0; n < 4; n++) bf[n] = *(short8*)&Bs[(wc + n * 16 + lr) * 32 + lk];
    #pragma unroll
    for (int m = 0; m < 4; m++)
      #pragma unroll
      for (int n = 0; n < 4; n++)
        MFMA16(af[m], bf[n], acc[m][n]);
    __syncthreads();
  }
}

// ============ 256x256 8-phase pipelined GEMM core (T2+T3+T4+T5) ============
// A [.][LD] row-major K-contig, B [.][LD] row-major K-contig; K = T*64.
// 8 waves (2M x 4N), per-wave output 128x64, LDS 128 KiB double-buffered.
// Swizzle: short-col ^= (row&7)<<3 (16B granule, 8-slot spread), both-sides.
// Stage schedule (deep-A): q1: Bl(t+1), q2: Bh(t+1), q3: -, q4: Al(t+2)+Ah(t+2).
// Waits: vmcnt(6) at q1-end (guards Bh(t)) and q4-end (guards A(t+1)+Bl(t+1)).
template<int LD, int T>
__device__ __forceinline__ void core8(const short* __restrict__ A, const short* __restrict__ Bv,
                                      size_t m0, size_t n0, int tid, short* sm,
                                      f32x4 (&acc)[8][4]) {
  const int w = tid >> 6, l = tid & 63;
  const int lr = l & 15;
  const int colsrc = ((l & 7) * 8) ^ ((l >> 3) << 3);
  const short* srcA = A  + (m0 + w * 8 + (l >> 3)) * (size_t)LD + colsrc;
  const short* srcB = Bv + (n0 + w * 8 + (l >> 3)) * (size_t)LD + colsrc;
  const int csw0 = ((l >> 4) * 8) ^ ((l & 7) << 3);
  const int csw1 = (32 + (l >> 4) * 8) ^ ((l & 7) << 3);
  const int AhalfOff = (w >> 2) * 8192 + lr * 64;
  const int BhalfOff = 16384 + ((w & 3) >> 1) * 8192 + ((w & 1) * 64 + lr) * 64;

  #define STA8(bf_, h_, q_, kt_) gld16(srcA + ((h_) * 128 + (q_) * 64) * (size_t)LD + (kt_) * 64, \
                                       &sm[(bf_) * 32768 + (h_) * 8192 + (q_) * 4096 + w * 512])
  #define STB8(bf_, h_, q_, kt_) gld16(srcB + ((h_) * 128 + (q_) * 64) * (size_t)LD + (kt_) * 64, \
                                       &sm[(bf_) * 32768 + 16384 + (h_) * 8192 + (q_) * 4096 + w * 512])

  #pragma unroll
  for (int m = 0; m < 8; m++)
    #pragma unroll
    for (int n = 0; n < 4; n++) acc[m][n] = (f32x4){0.f, 0.f, 0.f, 0.f};
  short8 Af[4][2], Bf0[2][2], Bf1[2][2];

  // prologue (12 loads, order matters): Al0,Ah0,Bl0 | then Bh0,Al1,Ah1 stay in flight
  STA8(0, 0, 0, 0); STA8(0, 1, 0, 0);   // Al0
  STA8(0, 0, 1, 0); STA8(0, 1, 1, 0);   // Ah0
  STB8(0, 0, 0, 0); STB8(0, 1, 0, 0);   // Bl0
  STB8(0, 0, 1, 0); STB8(0, 1, 1, 0);   // Bh0
  STA8(1, 0, 0, 1); STA8(1, 1, 0, 1);   // Al1
  STA8(1, 0, 1, 1); STA8(1, 1, 1, 1);   // Ah1
  VMCNT(6);
  SBAR();
  __builtin_amdgcn_sched_barrier(0);

  for (int t = 0; t < T; ++t) {
    const int buf = t & 1, nb = buf ^ 1;
    short* Ab = sm + buf * 32768 + AhalfOff;
    short* Bb = sm + buf * 32768 + BhalfOff;
    // ---- q1: quadrant (mh0, nh0); reads A-lows + B-lows (regions then dead)
    if (t + 1 < T) { STB8(nb, 0, 0, t + 1); STB8(nb, 1, 0, t + 1); }
    #pragma unroll
    for (int i = 0; i < 4; ++i) {
      Af[i][0] = *(const short8*)&Ab[i * 1024 + csw0];
      Af[i][1] = *(const short8*)&Ab[i * 1024 + csw1];
    }
    #pragma unroll
    for (int j = 0; j < 2; ++j) {
      Bf0[j][0] = *(const short8*)&Bb[j * 1024 + csw0];
      Bf0[j][1] = *(const short8*)&Bb[j * 1024 + csw1];
    }
    SBAR();
    __builtin_amdgcn_s_setprio(1);
    #pragma unroll
    for (int i = 0; i < 4; ++i)
      #pragma unroll
      for (int j = 0; j < 2; ++j) {
        MFMA16(Af[i][0], Bf0[j][0], acc[i][j]);
        MFMA16(Af[i][1], Bf0[j][1], acc[i][j]);
      }
    __builtin_amdgcn_s_setprio(0);
    if (t + 1 < T) { VMCNT(6); } else { VMCNT(0); }   // guards Bh(t) for q2
    SBAR();
    // ---- q2: quadrant (mh0, nh1); reads B-highs (region then dead)
    if (t + 1 < T) { STB8(nb, 0, 1, t + 1); STB8(nb, 1, 1, t + 1); }
    #pragma unroll
    for (int j = 0; j < 2; ++j) {
      Bf1[j][0] = *(const short8*)&Bb[2048 + j * 1024 + csw0];
      Bf1[j][1] = *(const short8*)&Bb[2048 + j * 1024 + csw1];
    }
    SBAR();
    __builtin_amdgcn_s_setprio(1);
    #pragma unroll
    for (int i = 0; i < 4; ++i)
      #pragma unroll
      for (int j = 0; j < 2; ++j) {
        MFMA16(Af[i][0], Bf1[j][0], acc[i][2 + j]);
        MFMA16(Af[i][1], Bf1[j][1], acc[i][2 + j]);
      }
    __builtin_amdgcn_s_setprio(0);
    SBAR();
    // ---- q3: quadrant (mh1, nh1); reads A-highs (region then dead); no stage
    #pragma unroll
    for (int i = 0; i < 4; ++i) {
      Af[i][0] = *(const short8*)&Ab[4096 + i * 1024 + csw0];
      Af[i][1] = *(const short8*)&Ab[4096 + i * 1024 + csw1];
    }
    SBAR();
    __builtin_amdgcn_s_setprio(1);
    #pragma unroll
    for (int i = 0; i < 4; ++i)
      #pragma unroll
      for (int j = 0; j < 2; ++j) {
        MFMA16(Af[i][0], Bf1[j][0], acc[4 + i][2 + j]);
        MFMA16(Af[i][1], Bf1[j][1], acc[4 + i][2 + j]);
      }
    __builtin_amdgcn_s_setprio(0);
    SBAR();
    // ---- q4: quadrant (mh1, nh0); register-only; stage A(t+2) into cur buf
    if (t + 2 < T) { STA8(buf, 0, 0, t + 2); STA8(buf, 1, 0, t + 2);
                     STA8(buf, 0, 1, t + 2); STA8(buf, 1, 1, t + 2); }
    __builtin_amdgcn_s_setprio(1);
    #pragma unroll
    for (int i = 0; i < 4; ++i)
      #pragma unroll
      for (int j = 0; j < 2; ++j) {
        MFMA16(Af[i][0], Bf0[j][0], acc[4 + i][j]);
        MFMA16(Af[i][1], Bf0[j][1], acc[4 + i][j]);
      }
    __builtin_amdgcn_s_setprio(0);
    if (t + 2 < T) { VMCNT(6); } else if (t + 1 < T) { VMCNT(2); } else { VMCNT(0); }
    SBAR();
    __builtin_amdgcn_sched_barrier(0);
  }
  #undef STA8
  #undef STB8
}

// ---------------- GEMM1 main (cols 0..2047): 8-phase 256x256 ----------------
__global__ __launch_bounds__(512, 2) void guv8_kernel(
    const short* __restrict__ xn, const short* __restrict__ W_uvT,
    const float* __restrict__ b_uv,
    short* __restrict__ u_out, short* __restrict__ vT_out)
{
  extern __shared__ __align__(16) short sm[];
  const size_t m0 = (size_t)blockIdx.x * 256;
  const size_t n0 = (size_t)blockIdx.y * 256;
  const int tid = threadIdx.x, w = tid >> 6, l = tid & 63;
  const int lr = l & 15;
  f32x4 acc[8][4];
  core8<DIMD, DIMD / 64>(xn, W_uvT, m0, n0, tid, sm, acc);
  const int rowb0 = (int)m0 + (w >> 2) * 128 + (l >> 4) * 4;
  const int colb0 = (int)n0 + (w & 3) * 64 + lr;
  if (n0 < 1024) {
    #pragma unroll
    for (int mf = 0; mf < 8; ++mf) {
      #pragma unroll
      for (int nf = 0; nf < 4; ++nf) {
        int col = colb0 + nf * 16;
        float bias = b_uv[col];
        #pragma unroll
        for (int r = 0; r < 4; ++r)
          u_out[(size_t)(rowb0 + mf * 16 + r) * EE + col] = f2bf(silu_f(acc[mf][nf][r] + bias));
      }
    }
  } else {
    #pragma unroll
    for (int mf = 0; mf < 8; ++mf) {
      int row = rowb0 + mf * 16;
      int bb = row >> 12, lb = row & (LLL - 1);
      #pragma unroll
      for (int nf = 0; nf < 4; ++nf) {
        int e = colb0 + nf * 16 - 1024;
        float bias = b_uv[e + 1024];
        short4 o;
        o.x = f2bf(silu_f(acc[mf][nf][0] + bias));
        o.y = f2bf(silu_f(acc[mf][nf][1] + bias));
        o.z = f2bf(silu_f(acc[mf][nf][2] + bias));
        o.w = f2bf(silu_f(acc[mf][nf][3] + bias));
        *(short4*)&vT_out[((size_t)bb * EE + e) * LLL + lb] = o;
      }
    }
  }
}

// ---------------- GEMM1 strip (cols 2048..2175 -> q,k): m97 core ----------------
__global__ __launch_bounds__(256) void qkstrip_kernel(
    const short* __restrict__ xn, const short* __restrict__ Wqk,
    const float* __restrict__ b_uv, const float* __restrict__ gamma, const float* __restrict__ beta,
    short* __restrict__ q_out, short* __restrict__ k_out)
{
  __shared__ __align__(16) short sm[8192];
  int tid = threadIdx.x;
  size_t m0 = (size_t)blockIdx.x * 128;
  f32x4 acc[4][4];
  gemm_core(xn, Wqk, DIMD, DIMD, DIMD, m0, 0, tid, sm, acc);
  int wid = tid >> 6, lane = tid & 63;
  int wr = (wid >> 1) * 64, wc = (wid & 1) * 64;
  int lr = lane & 15;
  #pragma unroll
  for (int m = 0; m < 4; m++) {
    #pragma unroll
    for (int n = 0; n < 4; n++) {
      int s = wc + n * 16 + lr;
      float bias = b_uv[2048 + s];
      float g0 = gamma[s], g1 = gamma[SSS + s], be0 = beta[s], be1 = beta[SSS + s];
      int rowb = (int)m0 + wr + m * 16 + (lane >> 4) * 4;
      #pragma unroll
      for (int r = 0; r < 4; r++) {
        float val = acc[m][n][r] + bias;
        q_out[(size_t)(rowb + r) * SSS + s] = f2bf(val * g0 + be0);
        k_out[(size_t)(rowb + r) * SSS + s] = f2bf(val * g1 + be1);
      }
    }
  }
}

// ---------------- QK^T -> P = relu(qk/sqrt(S))^2 (bf16) ----------------
__global__ __launch_bounds__(256) void gqk_kernel(
    const short* __restrict__ q, const short* __restrict__ k, short* __restrict__ P,
    long sq, long sk, long sp)
{
  __shared__ __align__(16) short sm[8192];
  int tid = threadIdx.x;
  const short* qz = q + (size_t)blockIdx.z * sq;
  const short* kz = k + (size_t)blockIdx.z * sk;
  short* Pz = P + (size_t)blockIdx.z * sp;
  size_t m0 = (size_t)blockIdx.x * 128, n0 = (size_t)blockIdx.y * 128;
  f32x4 acc[4][4];
  gemm_core(qz, kz, SSS, SSS, SSS, m0, n0, tid, sm, acc);
  int wid = tid >> 6, lane = tid & 63;
  int wr = (wid >> 1) * 64, wc = (wid & 1) * 64;
  int lr = lane & 15;
  const float scale = 0.08838834764831845f;
  #pragma unroll
  for (int m = 0; m < 4; m++) {
    #pragma unroll
    for (int n = 0; n < 4; n++) {
      int col = (int)n0 + wc + n * 16 + lr;
      int rowb = (int)m0 + wr + m * 16 + (lane >> 4) * 4;
      #pragma unroll
      for (int r = 0; r < 4; r++) {
        float v = fmaxf(acc[m][n][r] * scale, 0.f);
        Pz[(size_t)(rowb + r) * LLL + col] = f2bf(v * v);
      }
    }
  }
}

// ---------------- legacy PV (fallback tiers): m97 core ----------------
__global__ __launch_bounds__(256) void gpv_kernel(
    const short* __restrict__ P, const short* __restrict__ vT,
    const short* __restrict__ u, short* __restrict__ g,
    long sp, long sv, long su)
{
  __shared__ __align__(16) short sm[8192];
  int tid = threadIdx.x;
  const short* Pz = P + (size_t)blockIdx.z * sp;
  const short* vz = vT + (size_t)blockIdx.z * sv;
  const short* uz = u + (size_t)blockIdx.z * su;
  short* gz = g + (size_t)blockIdx.z * su;
  size_t m0 = (size_t)blockIdx.x * 128, n0 = (size_t)blockIdx.y * 128;
  f32x4 acc[4][4];
  gemm_core(Pz, vz, LLL, LLL, LLL, m0, n0, tid, sm, acc);
  int wid = tid >> 6, lane = tid & 63;
  int wr = (wid >> 1) * 64, wc = (wid & 1) * 64;
  int lr = lane & 15;
  #pragma unroll
  for (int m = 0; m < 4; m++) {
    #pragma unroll
    for (int n = 0; n < 4; n++) {
      int col = (int)n0 + wc + n * 16 + lr;
      int rowb = (int)m0 + wr + m * 16 + (lane >> 4) * 4;
      #pragma unroll
      for (int r = 0; r < 4; r++) {
        size_t idx = (size_t)(rowb + r) * EE + col;
        gz[idx] = f2bf(bf2f(uz[idx]) * acc[m][n][r]);
      }
    }
  }
}

// ---------------- PV, 256x256 8-phase (shared core) ----------------
__global__ __launch_bounds__(512, 2) void gpv8_kernel(
    const short* __restrict__ Pg, const short* __restrict__ vTg,
    const short* __restrict__ ug, short* __restrict__ gg)
{
  extern __shared__ __align__(16) short sm[];
  const int b = blockIdx.z;
  const size_t m0 = (size_t)blockIdx.x * 256;
  const size_t n0 = (size_t)blockIdx.y * 256;
  const short* A  = Pg  + (size_t)b * LLL * LLL;
  const short* Bv = vTg + (size_t)b * EE * LLL;
  const int tid = threadIdx.x, w = tid >> 6, l = tid & 63;
  const int lr = l & 15;
  f32x4 acc[8][4];
  core8<LLL, LLL / 64>(A, Bv, m0, n0, tid, sm, acc);
  const short* ub_ = ug + (size_t)b * LLL * EE;
  short* gb_ = gg + (size_t)b * LLL * EE;
  const int rowb0 = (int)m0 + (w >> 2) * 128 + (l >> 4) * 4;
  const int colb0 = (int)n0 + (w & 3) * 64 + lr;
  #pragma unroll
  for (int mf = 0; mf < 8; ++mf) {
    #pragma unroll
    for (int nf = 0; nf < 4; ++nf) {
      int col = colb0 + nf * 16;
      #pragma unroll
      for (int r = 0; r < 4; ++r) {
        size_t idx = (size_t)(rowb0 + mf * 16 + r) * EE + col;
        gb_[idx] = f2bf(bf2f(ub_[idx]) * acc[mf][nf][r]);
      }
    }
  }
}

// ---------------- GEMM2: g x W_outT + bias + residual (fp32 out) ----------------
__global__ __launch_bounds__(256) void gout_kernel(
    const short* __restrict__ A, const short* __restrict__ Bw,
    const float* __restrict__ b_out, const float* __restrict__ x,
    float* __restrict__ out)
{
  __shared__ __align__(16) short sm[8192];
  int tid = threadIdx.x;
  size_t m0 = (size_t)blockIdx.x * 128, n0 = (size_t)blockIdx.y * 128;
  f32x4 acc[4][4];
  gemm_core(A, Bw, EE, EE, EE, m0, n0, tid, sm, acc);
  int wid = tid >> 6, lane = tid & 63;
  int wr = (wid >> 1) * 64, wc = (wid & 1) * 64;
  int lr = lane & 15;
  #pragma unroll
  for (int m = 0; m < 4; m++) {
    #pragma unroll
    for (int n = 0; n < 4; n++) {
      int col = (int)n0 + wc + n * 16 + lr;
      float bias = b_out[col];
      int rowb = (int)m0 + wr + m * 16 + (lane >> 4) * 4;
      #pragma unroll
      for (int r = 0; r < 4; r++) {
        size_t idx = (size_t)(rowb + r) * DIMD + col;
        out[idx] = acc[m][n][r] + bias + x[idx];
      }
    }
  }
}

extern "C" void kernel_launch(void* const* d_in, const int* in_sizes, int n_in,
                              void* d_out, int out_size, void* d_ws, size_t ws_size,
                              hipStream_t stream) {
  const float* x     = (const float*)d_in[0];
  const float* W_uv  = (const float*)d_in[1];
  const float* b_uv  = (const float*)d_in[2];
  const float* gamma = (const float*)d_in[3];
  const float* beta  = (const float*)d_in[4];
  const float* W_out = (const float*)d_in[5];
  const float* b_out = (const float*)d_in[6];
  const float* ln_w  = (const float*)d_in[7];
  const float* ln_b  = (const float*)d_in[8];
  float* out = (float*)d_out;

  char* ws = (char*)d_ws;
  short* W_uvT  = (short*)(ws);
  short* W_outT = (short*)(ws + 2228224);
  short* xn     = (short*)(ws + 3276800);
  short* qb     = (short*)(ws + 20054016);
  short* kb     = (short*)(ws + 24248320);
  short* ub     = (short*)(ws + 28442624);
  short* vTb    = (short*)(ws + 61997056);
  short* gb     = (short*)(ws + 95551488);
  short* Pb     = (short*)(ws + 129105920);

  prep_kernel<<<dim3((NUV * DIMD + 255) / 256), 256, 0, stream>>>(W_uv, W_out, W_uvT, W_outT);
  ln_kernel<<<dim3(NROW), 256, 0, stream>>>(x, ln_w, ln_b, xn);
  guv8_kernel<<<dim3(NROW / 256, 8), 512, 131072, stream>>>(xn, W_uvT, b_uv, ub, vTb);
  qkstrip_kernel<<<dim3(NROW / 128), 256, 0, stream>>>(xn, W_uvT + (size_t)2048 * DIMD, b_uv, gamma, beta, qb, kb);

  const long SQ = (long)LLL * SSS;
  const long SP = (long)LLL * LLL;
  const long SV = (long)EE * LLL;
  const long SU = (long)LLL * EE;

  if (ws_size >= 129105920ull + 134217728ull) {
    gqk_kernel<<<dim3(32, 32, 4), 256, 0, stream>>>(qb, kb, Pb, SQ, SQ, SP);
    gpv8_kernel<<<dim3(16, 4, 4), 512, 131072, stream>>>(Pb, vTb, ub, gb);
  } else if (ws_size >= 129105920ull + 33554432ull) {
    for (int b = 0; b < 4; b++) {
      gqk_kernel<<<dim3(32, 32, 1), 256, 0, stream>>>(qb + (size_t)b * SQ, kb + (size_t)b * SQ, Pb, 0, 0, 0);
      gpv_kernel<<<dim3(32, 8, 1), 256, 0, stream>>>(Pb, vTb + (size_t)b * SV, ub + (size_t)b * SU, gb + (size_t)b * SU, 0, 0, 0);
    }
  } else {
    short* Pc = xn;
    for (int b = 0; b < 4; b++) {
      for (int h = 0; h < 2; h++) {
        size_t rowoff = (size_t)b * LLL + (size_t)h * 2048;
        gqk_kernel<<<dim3(16, 32, 1), 256, 0, stream>>>(qb + rowoff * SSS, kb + (size_t)b * SQ, Pc, 0, 0, 0);
        gpv_kernel<<<dim3(16, 8, 1), 256, 0, stream>>>(Pc, vTb + (size_t)b * SV, ub + rowoff * EE, gb + rowoff * EE, 0, 0, 0);
      }
    }
  }

  gout_kernel<<<dim3(NROW / 128, DIMD / 128), 256, 0, stream>>>(gb, W_outT, b_out, x, out);
}